// Round 2
// baseline (1089.222 us; speedup 1.0000x reference)
//
#include <hip/hip_runtime.h>

// Problem constants
// B=4, C_IN=C=64, H=W=128, K=3, SCALE=0.125, EPS=1e-5
#define NB 4
#define HWSZ 16384   // 128*128
#define WIDTH 128

// ---------------------------------------------------------------------------
// conv1x1: out[b][o][hw] = bias[o] + sum_c w[o*64+c] * in[b][c][hw]
// block = 256 threads = 4 (ot) x 64 (px); each block: 64 consecutive hw, all 64 o.
// ---------------------------------------------------------------------------
__global__ __launch_bounds__(256) void conv1x1_k(const float* __restrict__ in,
                                                 const float* __restrict__ w,
                                                 const float* __restrict__ bias,
                                                 float* __restrict__ out) {
  __shared__ float xs[64][64];
  __shared__ float wsm[64][64];
  int tid = threadIdx.x;
  int px = tid & 63, ot = tid >> 6;
  int bid = blockIdx.x;
  int b = bid >> 8;             // 256 tiles per batch (16384/64)
  int hw0 = (bid & 255) << 6;
#pragma unroll
  for (int it = 0; it < 16; ++it) {
    int c = (it << 2) + ot;
    xs[c][px] = in[(((b << 6) + c) << 14) + hw0 + px];
    ((float*)wsm)[(it << 8) + tid] = w[(it << 8) + tid];
  }
  __syncthreads();
  for (int oi = 0; oi < 16; ++oi) {
    int o = (oi << 2) + ot;
    float acc = bias[o];
#pragma unroll
    for (int c = 0; c < 64; ++c) acc = fmaf(wsm[o][c], xs[c][px], acc);
    out[(((b << 6) + o) << 14) + hw0 + px] = acc;
  }
}

// ---------------------------------------------------------------------------
// Fused attention + fold (pure gather, each attn element used exactly once).
// Decodes the module's raw-reshape index algebra:
//   attn flat f = (c*9+kk)*16384 + hw ; softmax over triples (3t..3t+2)
//   cols g = m*2^20 + n  where f = n*9 + m
//   fold: of[c2,y,x] = sum_{i,j} cols[g = (c2*9+i*3+j)*16384 + (y+1-i)*128 + (x+1-j)]
// Writes a[b][0..63]=of, a[b][64..127]=ob (the torch concat layout).
// ---------------------------------------------------------------------------
__device__ __forceinline__ void triel(const float* __restrict__ xqb,
                                      const float* __restrict__ fgb,
                                      const float* __restrict__ bgb,
                                      int fe, float& xv, float& sf, float& sb) {
  int u = fe >> 14;          // c*9 + kk  (< 576)
  int hwp = fe & 16383;
  int c = u / 9;
  int kk = u - c * 9;
  int ki = kk / 3;
  int kj = kk - ki * 3;
  int sy = (hwp >> 7) + ki - 1;
  int sx = (hwp & 127) + kj - 1;
  if (((unsigned)sy < 128u) && ((unsigned)sx < 128u)) {
    int off = (c << 14) + (sy << 7) + sx;
    float xv_ = xqb[off];
    xv = xv_;
    sf = xv_ * fgb[off];
    sb = xv_ - bgb[off];
  } else {
    xv = 0.f;
    sf = 0.f;
    sb = 0.f;
  }
}

__global__ __launch_bounds__(256) void attnfold_k(const float* __restrict__ xq,
                                                  const float* __restrict__ fgp,
                                                  const float* __restrict__ bgp,
                                                  float* __restrict__ a) {
  int gidx = blockIdx.x * 256 + threadIdx.x;  // (b*64 + c2)*16384 + hw
  int hw = gidx & 16383;
  int bc = gidx >> 14;
  int c2 = bc & 63;
  int b = bc >> 6;
  int y = hw >> 7, x = hw & 127;
  const float* xqb = xq + (b << 20);
  const float* fgb = fgp + (b << 20);
  const float* bgb = bgp + (b << 20);
  float accf = 0.f, accb = 0.f;
#pragma unroll
  for (int i = 0; i < 3; ++i) {
    int yp = y + 1 - i;
    if ((unsigned)yp >= 128u) continue;
#pragma unroll
    for (int j = 0; j < 3; ++j) {
      int xp = x + 1 - j;
      if ((unsigned)xp >= 128u) continue;
      int g = ((c2 * 9 + i * 3 + j) << 14) + (yp << 7) + xp;
      int m = g >> 20;          // 0..8
      int n = g & 1048575;      // 2^20 - 1
      int f = n * 9 + m;
      int q = f % 3;
      int f0 = f - q;
      float xv0, sf0, sb0, xv1, sf1, sb1, xv2, sf2, sb2;
      triel(xqb, fgb, bgb, f0,     xv0, sf0, sb0);
      triel(xqb, fgb, bgb, f0 + 1, xv1, sf1, sb1);
      triel(xqb, fgb, bgb, f0 + 2, xv2, sf2, sb2);
      float xsel = (q == 0) ? xv0 : ((q == 1) ? xv1 : xv2);
      // softmax over triple (forward branch: s = xu*fu)
      float mf = fmaxf(fmaxf(sf0, sf1), sf2);
      float ef0 = __expf(sf0 - mf), ef1 = __expf(sf1 - mf), ef2 = __expf(sf2 - mf);
      float self_f = (q == 0) ? ef0 : ((q == 1) ? ef1 : ef2);
      accf += self_f / (ef0 + ef1 + ef2) * xsel;
      // background branch: s = xu - bu
      float mb = fmaxf(fmaxf(sb0, sb1), sb2);
      float eb0 = __expf(sb0 - mb), eb1 = __expf(sb1 - mb), eb2 = __expf(sb2 - mb);
      float self_b = (q == 0) ? eb0 : ((q == 1) ? eb1 : eb2);
      accb += self_b / (eb0 + eb1 + eb2) * xsel;
    }
  }
  a[((b * 128 + c2) << 14) + hw] = accf * 0.125f;
  a[((b * 128 + 64 + c2) << 14) + hw] = accb * 0.125f;
}

// ---------------------------------------------------------------------------
// Tail A: y2 = conv1x1_w2( relu( bn1( groupedconv3_w1(a) + b1 ) ) ) + b2
// grouped conv: out channel o reads concat channels 2o, 2o+1.
// ---------------------------------------------------------------------------
__global__ __launch_bounds__(256) void tail1_k(const float* __restrict__ a,
                                               const float* __restrict__ w1,
                                               const float* __restrict__ b1,
                                               const float* __restrict__ g1,
                                               const float* __restrict__ be1,
                                               const float* __restrict__ w2,
                                               const float* __restrict__ b2,
                                               float* __restrict__ y2) {
  __shared__ float t1[64][65];
  __shared__ float w2s[64][64];
  int tid = threadIdx.x, px = tid & 63, ot = tid >> 6;
  int bid = blockIdx.x;
  int b = bid >> 8;
  int hw0 = (bid & 255) << 6;
  int y = hw0 >> 7;
  int x = (hw0 & 127) + px;
  const float invs = 1.0f / sqrtf(1.0f + 1e-5f);
#pragma unroll
  for (int it = 0; it < 16; ++it) ((float*)w2s)[(it << 8) + tid] = w2[(it << 8) + tid];
  for (int oi = 0; oi < 16; ++oi) {
    int o = (oi << 2) + ot;
    float acc = b1[o];
#pragma unroll
    for (int ic = 0; ic < 2; ++ic) {
      const float* ap = a + ((b * 128 + 2 * o + ic) << 14);
#pragma unroll
      for (int dy = 0; dy < 3; ++dy) {
        int yy = y + dy - 1;
        if ((unsigned)yy >= 128u) continue;
#pragma unroll
        for (int dx = 0; dx < 3; ++dx) {
          int xx = x + dx - 1;
          if ((unsigned)xx >= 128u) continue;
          acc = fmaf(ap[(yy << 7) + xx], w1[((o * 2 + ic) * 3 + dy) * 3 + dx], acc);
        }
      }
    }
    acc = acc * (g1[o] * invs) + be1[o];
    t1[o][px] = fmaxf(acc, 0.f);
  }
  __syncthreads();
  for (int oi = 0; oi < 16; ++oi) {
    int o = (oi << 2) + ot;
    float acc = b2[o];
#pragma unroll
    for (int c = 0; c < 64; ++c) acc = fmaf(w2s[o][c], t1[c][px], acc);
    y2[(((b << 6) + o) << 14) + hw0 + px] = acc;
  }
}

// ---------------------------------------------------------------------------
// Tail B: out = conv1x1_w4( relu( bn2( depthwise3_w3(y2) + b3 ) ) ) + b4
// ---------------------------------------------------------------------------
__global__ __launch_bounds__(256) void tail2_k(const float* __restrict__ y2,
                                               const float* __restrict__ w3,
                                               const float* __restrict__ b3,
                                               const float* __restrict__ g2,
                                               const float* __restrict__ be2,
                                               const float* __restrict__ w4,
                                               const float* __restrict__ b4,
                                               float* __restrict__ out) {
  __shared__ float t1[64][65];
  __shared__ float w4s[64][64];
  int tid = threadIdx.x, px = tid & 63, ot = tid >> 6;
  int bid = blockIdx.x;
  int b = bid >> 8;
  int hw0 = (bid & 255) << 6;
  int y = hw0 >> 7;
  int x = (hw0 & 127) + px;
  const float invs = 1.0f / sqrtf(1.0f + 1e-5f);
#pragma unroll
  for (int it = 0; it < 16; ++it) ((float*)w4s)[(it << 8) + tid] = w4[(it << 8) + tid];
  for (int oi = 0; oi < 16; ++oi) {
    int o = (oi << 2) + ot;
    float acc = b3[o];
    const float* yp2 = y2 + (((b << 6) + o) << 14);
#pragma unroll
    for (int dy = 0; dy < 3; ++dy) {
      int yy = y + dy - 1;
      if ((unsigned)yy >= 128u) continue;
#pragma unroll
      for (int dx = 0; dx < 3; ++dx) {
        int xx = x + dx - 1;
        if ((unsigned)xx >= 128u) continue;
        acc = fmaf(yp2[(yy << 7) + xx], w3[(o * 3 + dy) * 3 + dx], acc);
      }
    }
    acc = acc * (g2[o] * invs) + be2[o];
    t1[o][px] = fmaxf(acc, 0.f);
  }
  __syncthreads();
  for (int oi = 0; oi < 16; ++oi) {
    int o = (oi << 2) + ot;
    float acc = b4[o];
#pragma unroll
    for (int c = 0; c < 64; ++c) acc = fmaf(w4s[o][c], t1[c][px], acc);
    out[(((b << 6) + o) << 14) + hw0 + px] = acc;
  }
}

// ---------------------------------------------------------------------------
extern "C" void kernel_launch(void* const* d_in, const int* in_sizes, int n_in,
                              void* d_out, int out_size, void* d_ws, size_t ws_size,
                              hipStream_t stream) {
  (void)in_sizes; (void)n_in; (void)out_size; (void)ws_size;
  const float* x      = (const float*)d_in[0];
  const float* fg     = (const float*)d_in[1];
  const float* bg     = (const float*)d_in[2];
  const float* w_x    = (const float*)d_in[3];
  const float* bias_x = (const float*)d_in[4];
  const float* w_f    = (const float*)d_in[5];
  const float* bias_f = (const float*)d_in[6];
  const float* w_b    = (const float*)d_in[7];
  const float* bias_b = (const float*)d_in[8];
  const float* w1     = (const float*)d_in[9];
  const float* b1     = (const float*)d_in[10];
  const float* g1     = (const float*)d_in[11];
  const float* be1    = (const float*)d_in[12];
  const float* w2     = (const float*)d_in[13];
  const float* b2     = (const float*)d_in[14];
  const float* w3     = (const float*)d_in[15];
  const float* b3     = (const float*)d_in[16];
  const float* g2     = (const float*)d_in[17];
  const float* be2    = (const float*)d_in[18];
  const float* w4     = (const float*)d_in[19];
  const float* b4     = (const float*)d_in[20];
  float* out = (float*)d_out;
  float* ws  = (float*)d_ws;

  const size_t NCHW = (size_t)NB * 64 * HWSZ;  // 4,194,304 floats
  float* xq  = ws;
  float* fgp = ws + NCHW;
  float* bgp = ws + 2 * NCHW;
  float* a   = ws + 3 * NCHW;   // 2*NCHW floats (B,128,H,W)
  float* y2  = xq;              // xq dead after attnfold_k; reuse

  dim3 blk(256);
  conv1x1_k<<<NB * 256, blk, 0, stream>>>(x,  w_x, bias_x, xq);
  conv1x1_k<<<NB * 256, blk, 0, stream>>>(fg, w_f, bias_f, fgp);
  conv1x1_k<<<NB * 256, blk, 0, stream>>>(bg, w_b, bias_b, bgp);
  attnfold_k<<<NB * 64 * HWSZ / 256, blk, 0, stream>>>(xq, fgp, bgp, a);
  tail1_k<<<NB * 256, blk, 0, stream>>>(a, w1, b1, g1, be1, w2, b2, y2);
  tail2_k<<<NB * 256, blk, 0, stream>>>(y2, w3, b3, g2, be2, w4, b4, out);
}

// Round 3
// 630.491 us; speedup vs baseline: 1.7276x; 1.7276x over previous
//
#include <hip/hip_runtime.h>

// Problem constants: B=4, C_IN=C=64, H=W=128, K=3, SCALE=0.125, EPS=1e-5
#define NB 4
#define HWSZ 16384   // 128*128

// ---------------------------------------------------------------------------
// conv1x1: out[b][o][hw] = bias[o] + sum_c w[o*64+c] * in[b][c][hw]
// ---------------------------------------------------------------------------
__global__ __launch_bounds__(256) void conv1x1_k(const float* __restrict__ in,
                                                 const float* __restrict__ w,
                                                 const float* __restrict__ bias,
                                                 float* __restrict__ out) {
  __shared__ float xs[64][64];
  __shared__ float wsm[64][64];
  int tid = threadIdx.x;
  int px = tid & 63, ot = tid >> 6;
  int bid = blockIdx.x;
  int b = bid >> 8;
  int hw0 = (bid & 255) << 6;
#pragma unroll
  for (int it = 0; it < 16; ++it) {
    int c = (it << 2) + ot;
    xs[c][px] = in[(((b << 6) + c) << 14) + hw0 + px];
    ((float*)wsm)[(it << 8) + tid] = w[(it << 8) + tid];
  }
  __syncthreads();
  for (int oi = 0; oi < 16; ++oi) {
    int o = (oi << 2) + ot;
    float acc = bias[o];
#pragma unroll
    for (int c = 0; c < 64; ++c) acc = fmaf(wsm[o][c], xs[c][px], acc);
    out[(((b << 6) + o) << 14) + hw0 + px] = acc;
  }
}

// ---------------------------------------------------------------------------
// PASS A: attn compute, thread per n (triple-group). f = 9n+m, m=0..8.
// Decode: c = n>>14 (one channel per thread!), l = n&16383, t = 9l+m,
// kk = t>>14, hwp = t&16383, sy = (hwp>>7)+kk/3-1, sx = (hwp&127)+kk%3-1.
// Reads 9 consecutive positions per array (coalesced, 9x wave-local reuse).
// Writes cols[g = m*2^20 + n] (coalesced per-m planes), 0.125-scaled.
// ---------------------------------------------------------------------------
__global__ __launch_bounds__(256) void passA_k(const float* __restrict__ xq,
                                               const float* __restrict__ fgp,
                                               const float* __restrict__ bgp,
                                               float* __restrict__ colsF,
                                               float* __restrict__ colsB,
                                               int b0) {
  int bl = blockIdx.x >> 12;                       // local batch in chunk
  int n = ((blockIdx.x & 4095) << 8) + threadIdx.x;
  int b = b0 + bl;
  const float* xqb = xq + ((size_t)b << 20);
  const float* fgb = fgp + ((size_t)b << 20);
  const float* bgb = bgp + ((size_t)b << 20);
  float* cF = colsF + ((size_t)bl * 9 << 20);
  float* cB = colsB + ((size_t)bl * 9 << 20);
  int c = n >> 14;
  int l = n & 16383;
  int base = 9 * l;
  float xv[9], sf[9], sb[9];
#pragma unroll
  for (int m = 0; m < 9; ++m) {
    int t = base + m;
    int kk = t >> 14;                 // 0..8
    int hwp = t & 16383;
    int ki = kk / 3, kj = kk - 3 * ki;
    int sy = (hwp >> 7) + ki - 1;
    int sx = (hwp & 127) + kj - 1;
    if (((unsigned)sy < 128u) && ((unsigned)sx < 128u)) {
      int off = (c << 14) + (sy << 7) + sx;
      float xv_ = xqb[off];
      xv[m] = xv_;
      sf[m] = xv_ * fgb[off];
      sb[m] = xv_ - bgb[off];
    } else {
      xv[m] = 0.f; sf[m] = 0.f; sb[m] = 0.f;
    }
  }
#pragma unroll
  for (int tr = 0; tr < 3; ++tr) {
    int i0 = 3 * tr;
    float mf = fmaxf(fmaxf(sf[i0], sf[i0 + 1]), sf[i0 + 2]);
    float e0 = __expf(sf[i0] - mf), e1 = __expf(sf[i0 + 1] - mf), e2 = __expf(sf[i0 + 2] - mf);
    float rs = 0.125f / (e0 + e1 + e2);
    cF[((size_t)(i0 + 0) << 20) + n] = e0 * rs * xv[i0 + 0];
    cF[((size_t)(i0 + 1) << 20) + n] = e1 * rs * xv[i0 + 1];
    cF[((size_t)(i0 + 2) << 20) + n] = e2 * rs * xv[i0 + 2];
    float mb = fmaxf(fmaxf(sb[i0], sb[i0 + 1]), sb[i0 + 2]);
    float g0 = __expf(sb[i0] - mb), g1 = __expf(sb[i0 + 1] - mb), g2 = __expf(sb[i0 + 2] - mb);
    float rb = 0.125f / (g0 + g1 + g2);
    cB[((size_t)(i0 + 0) << 20) + n] = g0 * rb * xv[i0 + 0];
    cB[((size_t)(i0 + 1) << 20) + n] = g1 * rb * xv[i0 + 1];
    cB[((size_t)(i0 + 2) << 20) + n] = g2 * rb * xv[i0 + 2];
  }
}

// ---------------------------------------------------------------------------
// PASS B: fold gather. a[b][c2][y][x] = sum_w cols[(c2*9+w)*16384 + l_w],
// l_w = (y+1-i)*128 + (x+1-j), w = 3i+j (bounds-checked). Coalesced reads,
// each cols element read exactly once.
// ---------------------------------------------------------------------------
__global__ __launch_bounds__(256) void passB_k(const float* __restrict__ colsF,
                                               const float* __restrict__ colsB,
                                               float* __restrict__ a, int b0) {
  int bl = blockIdx.x >> 12;
  int idx = ((blockIdx.x & 4095) << 8) + threadIdx.x;  // c2*16384 + hw
  int b = b0 + bl;
  int c2 = idx >> 14;
  int hw = idx & 16383;
  int y = hw >> 7, x = hw & 127;
  const float* cF = colsF + ((size_t)bl * 9 << 20);
  const float* cB = colsB + ((size_t)bl * 9 << 20);
  float accf = 0.f, accb = 0.f;
#pragma unroll
  for (int i = 0; i < 3; ++i) {
    int yp = y + 1 - i;
    if ((unsigned)yp >= 128u) continue;
#pragma unroll
    for (int j = 0; j < 3; ++j) {
      int xp = x + 1 - j;
      if ((unsigned)xp >= 128u) continue;
      size_t g = ((size_t)(c2 * 9 + 3 * i + j) << 14) + (yp << 7) + xp;
      accf += cF[g];
      accb += cB[g];
    }
  }
  a[(((size_t)b * 128 + c2) << 14) + hw] = accf;
  a[(((size_t)b * 128 + 64 + c2) << 14) + hw] = accb;
}

// ---------------------------------------------------------------------------
// Fallback fused attn+fold (verified round 2) — used only if ws too small.
// ---------------------------------------------------------------------------
__device__ __forceinline__ void triel(const float* __restrict__ xqb,
                                      const float* __restrict__ fgb,
                                      const float* __restrict__ bgb,
                                      int fe, float& xv, float& sf, float& sb) {
  int u = fe >> 14;
  int hwp = fe & 16383;
  int c = u / 9;
  int kk = u - c * 9;
  int ki = kk / 3;
  int kj = kk - ki * 3;
  int sy = (hwp >> 7) + ki - 1;
  int sx = (hwp & 127) + kj - 1;
  if (((unsigned)sy < 128u) && ((unsigned)sx < 128u)) {
    int off = (c << 14) + (sy << 7) + sx;
    float xv_ = xqb[off];
    xv = xv_;
    sf = xv_ * fgb[off];
    sb = xv_ - bgb[off];
  } else {
    xv = 0.f; sf = 0.f; sb = 0.f;
  }
}

__global__ __launch_bounds__(256) void attnfold_k(const float* __restrict__ xq,
                                                  const float* __restrict__ fgp,
                                                  const float* __restrict__ bgp,
                                                  float* __restrict__ a) {
  int gidx = blockIdx.x * 256 + threadIdx.x;
  int hw = gidx & 16383;
  int bc = gidx >> 14;
  int c2 = bc & 63;
  int b = bc >> 6;
  int y = hw >> 7, x = hw & 127;
  const float* xqb = xq + (b << 20);
  const float* fgb = fgp + (b << 20);
  const float* bgb = bgp + (b << 20);
  float accf = 0.f, accb = 0.f;
#pragma unroll
  for (int i = 0; i < 3; ++i) {
    int yp = y + 1 - i;
    if ((unsigned)yp >= 128u) continue;
#pragma unroll
    for (int j = 0; j < 3; ++j) {
      int xp = x + 1 - j;
      if ((unsigned)xp >= 128u) continue;
      int g = ((c2 * 9 + i * 3 + j) << 14) + (yp << 7) + xp;
      int m = g >> 20;
      int n = g & 1048575;
      int f = n * 9 + m;
      int q = f % 3;
      int f0 = f - q;
      float xv0, sf0, sb0, xv1, sf1, sb1, xv2, sf2, sb2;
      triel(xqb, fgb, bgb, f0,     xv0, sf0, sb0);
      triel(xqb, fgb, bgb, f0 + 1, xv1, sf1, sb1);
      triel(xqb, fgb, bgb, f0 + 2, xv2, sf2, sb2);
      float xsel = (q == 0) ? xv0 : ((q == 1) ? xv1 : xv2);
      float mf = fmaxf(fmaxf(sf0, sf1), sf2);
      float ef0 = __expf(sf0 - mf), ef1 = __expf(sf1 - mf), ef2 = __expf(sf2 - mf);
      float self_f = (q == 0) ? ef0 : ((q == 1) ? ef1 : ef2);
      accf += self_f / (ef0 + ef1 + ef2) * xsel;
      float mb = fmaxf(fmaxf(sb0, sb1), sb2);
      float eb0 = __expf(sb0 - mb), eb1 = __expf(sb1 - mb), eb2 = __expf(sb2 - mb);
      float self_b = (q == 0) ? eb0 : ((q == 1) ? eb1 : eb2);
      accb += self_b / (eb0 + eb1 + eb2) * xsel;
    }
  }
  a[((b * 128 + c2) << 14) + hw] = accf * 0.125f;
  a[((b * 128 + 64 + c2) << 14) + hw] = accb * 0.125f;
}

// ---------------------------------------------------------------------------
// Tail A: y2 = conv1x1_w2( relu( bn1( groupedconv3_w1(a) + b1 ) ) ) + b2
// ---------------------------------------------------------------------------
__global__ __launch_bounds__(256) void tail1_k(const float* __restrict__ a,
                                               const float* __restrict__ w1,
                                               const float* __restrict__ b1,
                                               const float* __restrict__ g1,
                                               const float* __restrict__ be1,
                                               const float* __restrict__ w2,
                                               const float* __restrict__ b2,
                                               float* __restrict__ y2) {
  __shared__ float t1[64][65];
  __shared__ float w2s[64][64];
  int tid = threadIdx.x, px = tid & 63, ot = tid >> 6;
  int bid = blockIdx.x;
  int b = bid >> 8;
  int hw0 = (bid & 255) << 6;
  int y = hw0 >> 7;
  int x = (hw0 & 127) + px;
  const float invs = 1.0f / sqrtf(1.0f + 1e-5f);
#pragma unroll
  for (int it = 0; it < 16; ++it) ((float*)w2s)[(it << 8) + tid] = w2[(it << 8) + tid];
  for (int oi = 0; oi < 16; ++oi) {
    int o = (oi << 2) + ot;
    float acc = b1[o];
#pragma unroll
    for (int ic = 0; ic < 2; ++ic) {
      const float* ap = a + ((b * 128 + 2 * o + ic) << 14);
#pragma unroll
      for (int dy = 0; dy < 3; ++dy) {
        int yy = y + dy - 1;
        if ((unsigned)yy >= 128u) continue;
#pragma unroll
        for (int dx = 0; dx < 3; ++dx) {
          int xx = x + dx - 1;
          if ((unsigned)xx >= 128u) continue;
          acc = fmaf(ap[(yy << 7) + xx], w1[((o * 2 + ic) * 3 + dy) * 3 + dx], acc);
        }
      }
    }
    acc = acc * (g1[o] * invs) + be1[o];
    t1[o][px] = fmaxf(acc, 0.f);
  }
  __syncthreads();
  for (int oi = 0; oi < 16; ++oi) {
    int o = (oi << 2) + ot;
    float acc = b2[o];
#pragma unroll
    for (int c = 0; c < 64; ++c) acc = fmaf(w2s[o][c], t1[c][px], acc);
    y2[(((b << 6) + o) << 14) + hw0 + px] = acc;
  }
}

// ---------------------------------------------------------------------------
// Tail B: out = conv1x1_w4( relu( bn2( depthwise3_w3(y2) + b3 ) ) ) + b4
// ---------------------------------------------------------------------------
__global__ __launch_bounds__(256) void tail2_k(const float* __restrict__ y2,
                                               const float* __restrict__ w3,
                                               const float* __restrict__ b3,
                                               const float* __restrict__ g2,
                                               const float* __restrict__ be2,
                                               const float* __restrict__ w4,
                                               const float* __restrict__ b4,
                                               float* __restrict__ out) {
  __shared__ float t1[64][65];
  __shared__ float w4s[64][64];
  int tid = threadIdx.x, px = tid & 63, ot = tid >> 6;
  int bid = blockIdx.x;
  int b = bid >> 8;
  int hw0 = (bid & 255) << 6;
  int y = hw0 >> 7;
  int x = (hw0 & 127) + px;
  const float invs = 1.0f / sqrtf(1.0f + 1e-5f);
#pragma unroll
  for (int it = 0; it < 16; ++it) ((float*)w4s)[(it << 8) + tid] = w4[(it << 8) + tid];
  for (int oi = 0; oi < 16; ++oi) {
    int o = (oi << 2) + ot;
    float acc = b3[o];
    const float* yp2 = y2 + (((b << 6) + o) << 14);
#pragma unroll
    for (int dy = 0; dy < 3; ++dy) {
      int yy = y + dy - 1;
      if ((unsigned)yy >= 128u) continue;
#pragma unroll
      for (int dx = 0; dx < 3; ++dx) {
        int xx = x + dx - 1;
        if ((unsigned)xx >= 128u) continue;
        acc = fmaf(yp2[(yy << 7) + xx], w3[(o * 3 + dy) * 3 + dx], acc);
      }
    }
    acc = acc * (g2[o] * invs) + be2[o];
    t1[o][px] = fmaxf(acc, 0.f);
  }
  __syncthreads();
  for (int oi = 0; oi < 16; ++oi) {
    int o = (oi << 2) + ot;
    float acc = b4[o];
#pragma unroll
    for (int c = 0; c < 64; ++c) acc = fmaf(w4s[o][c], t1[c][px], acc);
    out[(((b << 6) + o) << 14) + hw0 + px] = acc;
  }
}

// ---------------------------------------------------------------------------
extern "C" void kernel_launch(void* const* d_in, const int* in_sizes, int n_in,
                              void* d_out, int out_size, void* d_ws, size_t ws_size,
                              hipStream_t stream) {
  (void)in_sizes; (void)n_in; (void)out_size;
  const float* x      = (const float*)d_in[0];
  const float* fg     = (const float*)d_in[1];
  const float* bg     = (const float*)d_in[2];
  const float* w_x    = (const float*)d_in[3];
  const float* bias_x = (const float*)d_in[4];
  const float* w_f    = (const float*)d_in[5];
  const float* bias_f = (const float*)d_in[6];
  const float* w_b    = (const float*)d_in[7];
  const float* bias_b = (const float*)d_in[8];
  const float* w1     = (const float*)d_in[9];
  const float* b1     = (const float*)d_in[10];
  const float* g1     = (const float*)d_in[11];
  const float* be1    = (const float*)d_in[12];
  const float* w2     = (const float*)d_in[13];
  const float* b2     = (const float*)d_in[14];
  const float* w3     = (const float*)d_in[15];
  const float* b3     = (const float*)d_in[16];
  const float* g2     = (const float*)d_in[17];
  const float* be2    = (const float*)d_in[18];
  const float* w4     = (const float*)d_in[19];
  const float* b4     = (const float*)d_in[20];
  float* out = (float*)d_out;
  float* ws  = (float*)d_ws;

  const size_t NCHWf = (size_t)NB * 64 * HWSZ;  // 4,194,304 floats
  float* xq  = ws;
  float* fgp = ws + NCHWf;
  float* bgp = ws + 2 * NCHWf;
  float* a   = ws + 3 * NCHWf;                  // 2*NCHWf floats
  float* colsbase = ws + 5 * NCHWf;
  float* y2  = xq;                              // xq dead after attn; reuse

  dim3 blk(256);
  conv1x1_k<<<NB * 256, blk, 0, stream>>>(x,  w_x, bias_x, xq);
  conv1x1_k<<<NB * 256, blk, 0, stream>>>(fg, w_f, bias_f, fgp);
  conv1x1_k<<<NB * 256, blk, 0, stream>>>(bg, w_b, bias_b, bgp);

  // cols workspace: per batch, colsF + colsB = 18M floats = 75.5 MB.
  const size_t usedB = 5 * NCHWf * 4;
  const size_t perBatchColsF = (size_t)18 << 20;  // floats
  size_t availF = (ws_size > usedB) ? (ws_size - usedB) / 4 : 0;
  int fit = (int)(availF / perBatchColsF);
  if (fit > NB) fit = NB;

  if (fit >= 1) {
    float* colsF = colsbase;
    float* colsB = colsbase + ((size_t)fit * 9 << 20);
    for (int b0 = 0; b0 < NB; b0 += fit) {
      int nb = (NB - b0 < fit) ? (NB - b0) : fit;
      passA_k<<<nb * 4096, blk, 0, stream>>>(xq, fgp, bgp, colsF, colsB, b0);
      passB_k<<<nb * 4096, blk, 0, stream>>>(colsF, colsB, a, b0);
    }
  } else {
    attnfold_k<<<NB * 64 * HWSZ / 256, blk, 0, stream>>>(xq, fgp, bgp, a);
  }

  tail1_k<<<NB * 256, blk, 0, stream>>>(a, w1, b1, g1, be1, w2, b2, y2);
  tail2_k<<<NB * 256, blk, 0, stream>>>(y2, w3, b3, g2, be2, w4, b4, out);
}

// Round 4
// 437.068 us; speedup vs baseline: 2.4921x; 1.4425x over previous
//
#include <hip/hip_runtime.h>

// Problem constants: B=4, C_IN=C=64, H=W=128, K=3, SCALE=0.125, EPS=1e-5
#define NB 4
#define HWSZ 16384   // 128*128

// ---------------------------------------------------------------------------
// pw_k: 1x1 conv (64 -> 64) + bias.  out[b][o][hw] = bias[o] + sum_c w[o][c]*in[b][c][hw]
// Block: 256 thr = 64 px4-lanes x 4 o-groups; covers 256 px x 32 o.
// Grid: B * 2 ochunks * 64 pxchunks = 512 blocks.
// Weights staged in LDS (8 KB), read as wave-uniform broadcasts (og fixed per wave).
// Input: coalesced float4 loads; output: coalesced float4 stores.
// ---------------------------------------------------------------------------
__global__ __launch_bounds__(256) void pw_k(const float* __restrict__ in,
                                            const float* __restrict__ w,
                                            const float* __restrict__ bias,
                                            float* __restrict__ out) {
  __shared__ float wls[32 * 64];
  int bid = blockIdx.x;
  int b = bid >> 7;
  int r = bid & 127;
  int oc = r >> 6;          // 0/1: which 32-o chunk
  int pc = r & 63;          // 256-px chunk
  int tid = threadIdx.x;
  int px4 = tid & 63;
  int og = tid >> 6;        // wave index: fixed within a 64-lane wave
  int px = (pc << 8) + (px4 << 2);
#pragma unroll
  for (int it = 0; it < 8; ++it)
    wls[(it << 8) + tid] = w[(oc << 11) + (it << 8) + tid];
  __syncthreads();
  int ob = (oc << 5) + (og << 3);
  float4 acc[8];
#pragma unroll
  for (int j = 0; j < 8; ++j) {
    float bv = bias[ob + j];
    acc[j] = make_float4(bv, bv, bv, bv);
  }
  const float* ip = in + (((size_t)b << 6) << 14) + px;
  const float* wp = wls + ((og << 3) << 6);
#pragma unroll 4
  for (int c = 0; c < 64; ++c) {
    float4 xv = *(const float4*)(ip + ((size_t)c << 14));
#pragma unroll
    for (int j = 0; j < 8; ++j) {
      float wv = wp[(j << 6) + c];
      acc[j].x = fmaf(wv, xv.x, acc[j].x);
      acc[j].y = fmaf(wv, xv.y, acc[j].y);
      acc[j].z = fmaf(wv, xv.z, acc[j].z);
      acc[j].w = fmaf(wv, xv.w, acc[j].w);
    }
  }
#pragma unroll
  for (int j = 0; j < 8; ++j)
    *(float4*)(out + (((size_t)(b << 6) + ob + j) << 14) + px) = acc[j];
}

// ---------------------------------------------------------------------------
// gconv1_k: grouped 3x3 (in 128ch, out 64ch, group=64: o reads ch 2o,2o+1)
//           + b1 + BN(g1,be1) + ReLU  ->  t1 (B,64,H,W)
// Block = (b, o, 8-row chunk); 256 thr = 32 px4 x 8 rows. Grid B*64*16 = 4096.
// ---------------------------------------------------------------------------
__global__ __launch_bounds__(256) void gconv1_k(const float* __restrict__ a,
                                                const float* __restrict__ w1,
                                                const float* __restrict__ b1,
                                                const float* __restrict__ g1,
                                                const float* __restrict__ be1,
                                                float* __restrict__ t1) {
  int bid = blockIdx.x;
  int b = bid >> 10;
  int r = bid & 1023;
  int o = r >> 4;
  int rc = r & 15;
  int tid = threadIdx.x;
  int px4 = tid & 31;
  int ry = tid >> 5;
  int y = (rc << 3) + ry;
  int x0 = px4 << 2;
  float bv = b1[o];
  float4 acc = make_float4(bv, bv, bv, bv);
#pragma unroll
  for (int ic = 0; ic < 2; ++ic) {
    const float* ap = a + ((size_t)(b * 128 + 2 * o + ic) << 14);
    const float* wr0 = w1 + o * 18 + ic * 9;
#pragma unroll
    for (int dy = 0; dy < 3; ++dy) {
      int yy = y + dy - 1;
      if ((unsigned)yy >= 128u) continue;
      const float* row = ap + (yy << 7);
      float4 mid = *(const float4*)(row + x0);
      float lf = (px4 > 0) ? row[x0 - 1] : 0.f;
      float rt = (px4 < 31) ? row[x0 + 4] : 0.f;
      float wa = wr0[dy * 3 + 0], wb = wr0[dy * 3 + 1], wc = wr0[dy * 3 + 2];
      acc.x += wa * lf    + wb * mid.x + wc * mid.y;
      acc.y += wa * mid.x + wb * mid.y + wc * mid.z;
      acc.z += wa * mid.y + wb * mid.z + wc * mid.w;
      acc.w += wa * mid.z + wb * mid.w + wc * rt;
    }
  }
  const float invs = 0.9999950000374997f;  // 1/sqrt(1+1e-5)
  float s = g1[o] * invs, be = be1[o];
  acc.x = fmaxf(acc.x * s + be, 0.f);
  acc.y = fmaxf(acc.y * s + be, 0.f);
  acc.z = fmaxf(acc.z * s + be, 0.f);
  acc.w = fmaxf(acc.w * s + be, 0.f);
  *(float4*)(t1 + (((size_t)(b << 6) + o) << 14) + (y << 7) + x0) = acc;
}

// ---------------------------------------------------------------------------
// dconv_k: depthwise 3x3 + b3 + BN(g2,be2) + ReLU -> t2 (B,64,H,W)
// ---------------------------------------------------------------------------
__global__ __launch_bounds__(256) void dconv_k(const float* __restrict__ y2,
                                               const float* __restrict__ w3,
                                               const float* __restrict__ b3,
                                               const float* __restrict__ g2,
                                               const float* __restrict__ be2,
                                               float* __restrict__ t2) {
  int bid = blockIdx.x;
  int b = bid >> 10;
  int r = bid & 1023;
  int o = r >> 4;
  int rc = r & 15;
  int tid = threadIdx.x;
  int px4 = tid & 31;
  int ry = tid >> 5;
  int y = (rc << 3) + ry;
  int x0 = px4 << 2;
  float bv = b3[o];
  float4 acc = make_float4(bv, bv, bv, bv);
  const float* ap = y2 + (((size_t)(b << 6) + o) << 14);
  const float* wr0 = w3 + o * 9;
#pragma unroll
  for (int dy = 0; dy < 3; ++dy) {
    int yy = y + dy - 1;
    if ((unsigned)yy >= 128u) continue;
    const float* row = ap + (yy << 7);
    float4 mid = *(const float4*)(row + x0);
    float lf = (px4 > 0) ? row[x0 - 1] : 0.f;
    float rt = (px4 < 31) ? row[x0 + 4] : 0.f;
    float wa = wr0[dy * 3 + 0], wb = wr0[dy * 3 + 1], wc = wr0[dy * 3 + 2];
    acc.x += wa * lf    + wb * mid.x + wc * mid.y;
    acc.y += wa * mid.x + wb * mid.y + wc * mid.z;
    acc.z += wa * mid.y + wb * mid.z + wc * mid.w;
    acc.w += wa * mid.z + wb * mid.w + wc * rt;
  }
  const float invs = 0.9999950000374997f;
  float s = g2[o] * invs, be = be2[o];
  acc.x = fmaxf(acc.x * s + be, 0.f);
  acc.y = fmaxf(acc.y * s + be, 0.f);
  acc.z = fmaxf(acc.z * s + be, 0.f);
  acc.w = fmaxf(acc.w * s + be, 0.f);
  *(float4*)(t2 + (((size_t)(b << 6) + o) << 14) + (y << 7) + x0) = acc;
}

// ---------------------------------------------------------------------------
// PASS A: attn compute, thread per n (triple-group). f = 9n+m, m=0..8.
// c = n>>14 (one channel per thread), l = n&16383, t = 9l+m.
// Reads 9 near-consecutive positions per array; writes cols[g=m*2^20+n]
// (coalesced per-m planes), 0.125-scaled.
// ---------------------------------------------------------------------------
__global__ __launch_bounds__(256) void passA_k(const float* __restrict__ xq,
                                               const float* __restrict__ fgp,
                                               const float* __restrict__ bgp,
                                               float* __restrict__ colsF,
                                               float* __restrict__ colsB,
                                               int b0) {
  int bl = blockIdx.x >> 12;
  int n = ((blockIdx.x & 4095) << 8) + threadIdx.x;
  int b = b0 + bl;
  const float* xqb = xq + ((size_t)b << 20);
  const float* fgb = fgp + ((size_t)b << 20);
  const float* bgb = bgp + ((size_t)b << 20);
  float* cF = colsF + ((size_t)bl * 9 << 20);
  float* cB = colsB + ((size_t)bl * 9 << 20);
  int c = n >> 14;
  int l = n & 16383;
  int base = 9 * l;
  float xv[9], sf[9], sb[9];
#pragma unroll
  for (int m = 0; m < 9; ++m) {
    int t = base + m;
    int kk = t >> 14;
    int hwp = t & 16383;
    int ki = kk / 3, kj = kk - 3 * ki;
    int sy = (hwp >> 7) + ki - 1;
    int sx = (hwp & 127) + kj - 1;
    if (((unsigned)sy < 128u) && ((unsigned)sx < 128u)) {
      int off = (c << 14) + (sy << 7) + sx;
      float xv_ = xqb[off];
      xv[m] = xv_;
      sf[m] = xv_ * fgb[off];
      sb[m] = xv_ - bgb[off];
    } else {
      xv[m] = 0.f; sf[m] = 0.f; sb[m] = 0.f;
    }
  }
#pragma unroll
  for (int tr = 0; tr < 3; ++tr) {
    int i0 = 3 * tr;
    float mf = fmaxf(fmaxf(sf[i0], sf[i0 + 1]), sf[i0 + 2]);
    float e0 = __expf(sf[i0] - mf), e1 = __expf(sf[i0 + 1] - mf), e2 = __expf(sf[i0 + 2] - mf);
    float rs = 0.125f / (e0 + e1 + e2);
    cF[((size_t)(i0 + 0) << 20) + n] = e0 * rs * xv[i0 + 0];
    cF[((size_t)(i0 + 1) << 20) + n] = e1 * rs * xv[i0 + 1];
    cF[((size_t)(i0 + 2) << 20) + n] = e2 * rs * xv[i0 + 2];
    float mb = fmaxf(fmaxf(sb[i0], sb[i0 + 1]), sb[i0 + 2]);
    float g0 = __expf(sb[i0] - mb), g1 = __expf(sb[i0 + 1] - mb), g2 = __expf(sb[i0 + 2] - mb);
    float rb = 0.125f / (g0 + g1 + g2);
    cB[((size_t)(i0 + 0) << 20) + n] = g0 * rb * xv[i0 + 0];
    cB[((size_t)(i0 + 1) << 20) + n] = g1 * rb * xv[i0 + 1];
    cB[((size_t)(i0 + 2) << 20) + n] = g2 * rb * xv[i0 + 2];
  }
}

// ---------------------------------------------------------------------------
// PASS B: fold gather -> a (B,128,H,W), concat layout (of: 0..63, ob: 64..127)
// ---------------------------------------------------------------------------
__global__ __launch_bounds__(256) void passB_k(const float* __restrict__ colsF,
                                               const float* __restrict__ colsB,
                                               float* __restrict__ a, int b0) {
  int bl = blockIdx.x >> 12;
  int idx = ((blockIdx.x & 4095) << 8) + threadIdx.x;
  int b = b0 + bl;
  int c2 = idx >> 14;
  int hw = idx & 16383;
  int y = hw >> 7, x = hw & 127;
  const float* cF = colsF + ((size_t)bl * 9 << 20);
  const float* cB = colsB + ((size_t)bl * 9 << 20);
  float accf = 0.f, accb = 0.f;
#pragma unroll
  for (int i = 0; i < 3; ++i) {
    int yp = y + 1 - i;
    if ((unsigned)yp >= 128u) continue;
#pragma unroll
    for (int j = 0; j < 3; ++j) {
      int xp = x + 1 - j;
      if ((unsigned)xp >= 128u) continue;
      size_t g = ((size_t)(c2 * 9 + 3 * i + j) << 14) + (yp << 7) + xp;
      accf += cF[g];
      accb += cB[g];
    }
  }
  a[(((size_t)b * 128 + c2) << 14) + hw] = accf;
  a[(((size_t)b * 128 + 64 + c2) << 14) + hw] = accb;
}

// ---------------------------------------------------------------------------
// Fallback fused attn+fold (verified) — used only if ws too small.
// ---------------------------------------------------------------------------
__device__ __forceinline__ void triel(const float* __restrict__ xqb,
                                      const float* __restrict__ fgb,
                                      const float* __restrict__ bgb,
                                      int fe, float& xv, float& sf, float& sb) {
  int u = fe >> 14;
  int hwp = fe & 16383;
  int c = u / 9;
  int kk = u - c * 9;
  int ki = kk / 3;
  int kj = kk - ki * 3;
  int sy = (hwp >> 7) + ki - 1;
  int sx = (hwp & 127) + kj - 1;
  if (((unsigned)sy < 128u) && ((unsigned)sx < 128u)) {
    int off = (c << 14) + (sy << 7) + sx;
    float xv_ = xqb[off];
    xv = xv_;
    sf = xv_ * fgb[off];
    sb = xv_ - bgb[off];
  } else {
    xv = 0.f; sf = 0.f; sb = 0.f;
  }
}

__global__ __launch_bounds__(256) void attnfold_k(const float* __restrict__ xq,
                                                  const float* __restrict__ fgp,
                                                  const float* __restrict__ bgp,
                                                  float* __restrict__ a) {
  int gidx = blockIdx.x * 256 + threadIdx.x;
  int hw = gidx & 16383;
  int bc = gidx >> 14;
  int c2 = bc & 63;
  int b = bc >> 6;
  int y = hw >> 7, x = hw & 127;
  const float* xqb = xq + (b << 20);
  const float* fgb = fgp + (b << 20);
  const float* bgb = bgp + (b << 20);
  float accf = 0.f, accb = 0.f;
#pragma unroll
  for (int i = 0; i < 3; ++i) {
    int yp = y + 1 - i;
    if ((unsigned)yp >= 128u) continue;
#pragma unroll
    for (int j = 0; j < 3; ++j) {
      int xp = x + 1 - j;
      if ((unsigned)xp >= 128u) continue;
      int g = ((c2 * 9 + i * 3 + j) << 14) + (yp << 7) + xp;
      int m = g >> 20;
      int n = g & 1048575;
      int f = n * 9 + m;
      int q = f % 3;
      int f0 = f - q;
      float xv0, sf0, sb0, xv1, sf1, sb1, xv2, sf2, sb2;
      triel(xqb, fgb, bgb, f0,     xv0, sf0, sb0);
      triel(xqb, fgb, bgb, f0 + 1, xv1, sf1, sb1);
      triel(xqb, fgb, bgb, f0 + 2, xv2, sf2, sb2);
      float xsel = (q == 0) ? xv0 : ((q == 1) ? xv1 : xv2);
      float mf = fmaxf(fmaxf(sf0, sf1), sf2);
      float ef0 = __expf(sf0 - mf), ef1 = __expf(sf1 - mf), ef2 = __expf(sf2 - mf);
      float self_f = (q == 0) ? ef0 : ((q == 1) ? ef1 : ef2);
      accf += self_f / (ef0 + ef1 + ef2) * xsel;
      float mb = fmaxf(fmaxf(sb0, sb1), sb2);
      float eb0 = __expf(sb0 - mb), eb1 = __expf(sb1 - mb), eb2 = __expf(sb2 - mb);
      float self_b = (q == 0) ? eb0 : ((q == 1) ? eb1 : eb2);
      accb += self_b / (eb0 + eb1 + eb2) * xsel;
    }
  }
  a[((b * 128 + c2) << 14) + hw] = accf * 0.125f;
  a[((b * 128 + 64 + c2) << 14) + hw] = accb * 0.125f;
}

// ---------------------------------------------------------------------------
extern "C" void kernel_launch(void* const* d_in, const int* in_sizes, int n_in,
                              void* d_out, int out_size, void* d_ws, size_t ws_size,
                              hipStream_t stream) {
  (void)in_sizes; (void)n_in; (void)out_size;
  const float* x      = (const float*)d_in[0];
  const float* fg     = (const float*)d_in[1];
  const float* bg     = (const float*)d_in[2];
  const float* w_x    = (const float*)d_in[3];
  const float* bias_x = (const float*)d_in[4];
  const float* w_f    = (const float*)d_in[5];
  const float* bias_f = (const float*)d_in[6];
  const float* w_b    = (const float*)d_in[7];
  const float* bias_b = (const float*)d_in[8];
  const float* w1     = (const float*)d_in[9];
  const float* b1     = (const float*)d_in[10];
  const float* g1     = (const float*)d_in[11];
  const float* be1    = (const float*)d_in[12];
  const float* w2     = (const float*)d_in[13];
  const float* b2     = (const float*)d_in[14];
  const float* w3     = (const float*)d_in[15];
  const float* b3     = (const float*)d_in[16];
  const float* g2     = (const float*)d_in[17];
  const float* be2    = (const float*)d_in[18];
  const float* w4     = (const float*)d_in[19];
  const float* b4     = (const float*)d_in[20];
  float* out = (float*)d_out;
  float* ws  = (float*)d_ws;

  const size_t NCHWf = (size_t)NB * 64 * HWSZ;  // 4,194,304 floats
  float* xq  = ws;
  float* fgp = ws + NCHWf;
  float* bgp = ws + 2 * NCHWf;
  float* a   = ws + 3 * NCHWf;                  // 2*NCHWf floats
  float* colsbase = ws + 5 * NCHWf;
  // dead-buffer reuse for the tail chain:
  float* t1 = fgp;   // fgp dead after passA
  float* y2 = xq;    // xq dead after passA
  float* t2 = bgp;   // bgp dead after passA

  dim3 blk(256);
  pw_k<<<NB * 128, blk, 0, stream>>>(x,  w_x, bias_x, xq);
  pw_k<<<NB * 128, blk, 0, stream>>>(fg, w_f, bias_f, fgp);
  pw_k<<<NB * 128, blk, 0, stream>>>(bg, w_b, bias_b, bgp);

  // cols workspace: per batch, colsF + colsB = 18M floats = 75.5 MB.
  const size_t usedB = 5 * NCHWf * 4;
  const size_t perBatchColsF = (size_t)18 << 20;  // floats
  size_t availF = (ws_size > usedB) ? (ws_size - usedB) / 4 : 0;
  int fit = (int)(availF / perBatchColsF);
  if (fit > NB) fit = NB;

  if (fit >= 1) {
    float* colsF = colsbase;
    float* colsB = colsbase + ((size_t)fit * 9 << 20);
    for (int b0 = 0; b0 < NB; b0 += fit) {
      int nb = (NB - b0 < fit) ? (NB - b0) : fit;
      passA_k<<<nb * 4096, blk, 0, stream>>>(xq, fgp, bgp, colsF, colsB, b0);
      passB_k<<<nb * 4096, blk, 0, stream>>>(colsF, colsB, a, b0);
    }
  } else {
    attnfold_k<<<NB * 64 * HWSZ / 256, blk, 0, stream>>>(xq, fgp, bgp, a);
  }

  gconv1_k<<<NB * 1024, blk, 0, stream>>>(a, w1, b1, g1, be1, t1);
  pw_k<<<NB * 128, blk, 0, stream>>>(t1, w2, b2, y2);
  dconv_k<<<NB * 1024, blk, 0, stream>>>(y2, w3, b3, g2, be2, t2);
  pw_k<<<NB * 128, blk, 0, stream>>>(t2, w4, b4, out);
}

// Round 5
// 388.658 us; speedup vs baseline: 2.8025x; 1.1246x over previous
//
#include <hip/hip_runtime.h>

// Problem constants: B=4, C_IN=C=64, H=W=128, K=3, SCALE=0.125, EPS=1e-5
#define NB 4
#define HWSZ 16384   // 128*128

// 16B vector with only 4B alignment guarantee (gfx9+ supports unaligned dwordx4)
typedef float f4u __attribute__((ext_vector_type(4), aligned(4)));

// ---------------------------------------------------------------------------
// pw_k: 1x1 conv (64 -> 64) + bias. Block: 256 thr = 64 px4-lanes x 4 og;
// covers 256 px x 16 o. Grid: B * 4 ochunks * 64 pxchunks = 1024 blocks.
// ---------------------------------------------------------------------------
__global__ __launch_bounds__(256) void pw_k(const float* __restrict__ in,
                                            const float* __restrict__ w,
                                            const float* __restrict__ bias,
                                            float* __restrict__ out) {
  __shared__ float wls[16 * 64];
  int bid = blockIdx.x;
  int b = bid >> 8;
  int r = bid & 255;
  int oc = r >> 6;          // 0..3: which 16-o chunk
  int pc = r & 63;          // 256-px chunk
  int tid = threadIdx.x;
  int px4 = tid & 63;
  int og = tid >> 6;        // wave index: uniform within wave
  int px = (pc << 8) + (px4 << 2);
#pragma unroll
  for (int it = 0; it < 4; ++it)
    wls[(it << 8) + tid] = w[(oc << 10) + (it << 8) + tid];
  __syncthreads();
  int ob = (oc << 4) + (og << 2);
  float4 acc[4];
#pragma unroll
  for (int j = 0; j < 4; ++j) {
    float bv = bias[ob + j];
    acc[j] = make_float4(bv, bv, bv, bv);
  }
  const float* ip = in + (((size_t)b << 6) << 14) + px;
  const float* wp = wls + ((og << 2) << 6);
#pragma unroll 4
  for (int cc = 0; cc < 64; ++cc) {
    float4 xv = *(const float4*)(ip + ((size_t)cc << 14));
#pragma unroll
    for (int j = 0; j < 4; ++j) {
      float wv = wp[(j << 6) + cc];
      acc[j].x = fmaf(wv, xv.x, acc[j].x);
      acc[j].y = fmaf(wv, xv.y, acc[j].y);
      acc[j].z = fmaf(wv, xv.z, acc[j].z);
      acc[j].w = fmaf(wv, xv.w, acc[j].w);
    }
  }
#pragma unroll
  for (int j = 0; j < 4; ++j)
    *(float4*)(out + (((size_t)(b << 6) + ob + j) << 14) + px) = acc[j];
}

// ---------------------------------------------------------------------------
// gconv1_k: grouped 3x3 (o reads concat ch 2o,2o+1) + b1 + BN + ReLU -> t1
// ---------------------------------------------------------------------------
__global__ __launch_bounds__(256) void gconv1_k(const float* __restrict__ a,
                                                const float* __restrict__ w1,
                                                const float* __restrict__ b1,
                                                const float* __restrict__ g1,
                                                const float* __restrict__ be1,
                                                float* __restrict__ t1) {
  int bid = blockIdx.x;
  int b = bid >> 10;
  int r = bid & 1023;
  int o = r >> 4;
  int rc = r & 15;
  int tid = threadIdx.x;
  int px4 = tid & 31;
  int ry = tid >> 5;
  int y = (rc << 3) + ry;
  int x0 = px4 << 2;
  float bv = b1[o];
  float4 acc = make_float4(bv, bv, bv, bv);
#pragma unroll
  for (int ic = 0; ic < 2; ++ic) {
    const float* ap = a + ((size_t)(b * 128 + 2 * o + ic) << 14);
    const float* wr0 = w1 + o * 18 + ic * 9;
#pragma unroll
    for (int dy = 0; dy < 3; ++dy) {
      int yy = y + dy - 1;
      if ((unsigned)yy >= 128u) continue;
      const float* row = ap + (yy << 7);
      float4 mid = *(const float4*)(row + x0);
      float lf = (px4 > 0) ? row[x0 - 1] : 0.f;
      float rt = (px4 < 31) ? row[x0 + 4] : 0.f;
      float wa = wr0[dy * 3 + 0], wb = wr0[dy * 3 + 1], wc = wr0[dy * 3 + 2];
      acc.x += wa * lf    + wb * mid.x + wc * mid.y;
      acc.y += wa * mid.x + wb * mid.y + wc * mid.z;
      acc.z += wa * mid.y + wb * mid.z + wc * mid.w;
      acc.w += wa * mid.z + wb * mid.w + wc * rt;
    }
  }
  const float invs = 0.9999950000374997f;  // 1/sqrt(1+1e-5)
  float s = g1[o] * invs, be = be1[o];
  acc.x = fmaxf(acc.x * s + be, 0.f);
  acc.y = fmaxf(acc.y * s + be, 0.f);
  acc.z = fmaxf(acc.z * s + be, 0.f);
  acc.w = fmaxf(acc.w * s + be, 0.f);
  *(float4*)(t1 + (((size_t)(b << 6) + o) << 14) + (y << 7) + x0) = acc;
}

// ---------------------------------------------------------------------------
// dconv_k: depthwise 3x3 + b3 + BN + ReLU -> t2
// ---------------------------------------------------------------------------
__global__ __launch_bounds__(256) void dconv_k(const float* __restrict__ y2,
                                               const float* __restrict__ w3,
                                               const float* __restrict__ b3,
                                               const float* __restrict__ g2,
                                               const float* __restrict__ be2,
                                               float* __restrict__ t2) {
  int bid = blockIdx.x;
  int b = bid >> 10;
  int r = bid & 1023;
  int o = r >> 4;
  int rc = r & 15;
  int tid = threadIdx.x;
  int px4 = tid & 31;
  int ry = tid >> 5;
  int y = (rc << 3) + ry;
  int x0 = px4 << 2;
  float bv = b3[o];
  float4 acc = make_float4(bv, bv, bv, bv);
  const float* ap = y2 + (((size_t)(b << 6) + o) << 14);
  const float* wr0 = w3 + o * 9;
#pragma unroll
  for (int dy = 0; dy < 3; ++dy) {
    int yy = y + dy - 1;
    if ((unsigned)yy >= 128u) continue;
    const float* row = ap + (yy << 7);
    float4 mid = *(const float4*)(row + x0);
    float lf = (px4 > 0) ? row[x0 - 1] : 0.f;
    float rt = (px4 < 31) ? row[x0 + 4] : 0.f;
    float wa = wr0[dy * 3 + 0], wb = wr0[dy * 3 + 1], wc = wr0[dy * 3 + 2];
    acc.x += wa * lf    + wb * mid.x + wc * mid.y;
    acc.y += wa * mid.x + wb * mid.y + wc * mid.z;
    acc.z += wa * mid.y + wb * mid.z + wc * mid.w;
    acc.w += wa * mid.z + wb * mid.w + wc * rt;
  }
  const float invs = 0.9999950000374997f;
  float s = g2[o] * invs, be = be2[o];
  acc.x = fmaxf(acc.x * s + be, 0.f);
  acc.y = fmaxf(acc.y * s + be, 0.f);
  acc.z = fmaxf(acc.z * s + be, 0.f);
  acc.w = fmaxf(acc.w * s + be, 0.f);
  *(float4*)(t2 + (((size_t)(b << 6) + o) << 14) + (y << 7) + x0) = acc;
}

// ---------------------------------------------------------------------------
// PASS A (4-wide): thread handles n0..n0+3 (same channel c = n0>>14).
// t = 9l+m; within one kk region, address off = base0 + (t - t0) is LINEAR,
// so the 36 reads per array are contiguous: load per-q 9-float windows with
// two 16B + one scalar load, mask boundary elements in VALU.
// Writes cols planes as aligned float4 (n0 % 4 == 0).
// ---------------------------------------------------------------------------
__global__ __launch_bounds__(256) void passA_k(const float* __restrict__ xq,
                                               const float* __restrict__ fgp,
                                               const float* __restrict__ bgp,
                                               float* __restrict__ colsF,
                                               float* __restrict__ colsB,
                                               int b0) {
  int bl = blockIdx.x >> 10;
  int n0 = (((blockIdx.x & 1023) << 8) + threadIdx.x) << 2;
  int b = b0 + bl;
  const float* xqb = xq + ((size_t)b << 20);
  const float* fgb = fgp + ((size_t)b << 20);
  const float* bgb = bgp + ((size_t)b << 20);
  float* cF = colsF + ((size_t)bl * 9 << 20);
  float* cB = colsB + ((size_t)bl * 9 << 20);
  int c = n0 >> 14;
  int l0 = n0 & 16383;
  int t0 = 9 * l0;
  int r0 = t0 & 16383;
  int kk0 = t0 >> 14;
  float resF[9][4], resB[9][4];

  if (r0 <= 16348) {
    // fast path: whole 36-range in one kk region
    int ki = kk0 / 3, kj = kk0 - 3 * ki;
    int base0 = (c << 14) + r0 + ((ki - 1) << 7) + (kj - 1);
    int kj0 = (kj == 0), kj2 = (kj == 2), ki0 = (ki == 0), ki2 = (ki == 2);
#pragma unroll
    for (int q = 0; q < 4; ++q) {
      int hq = r0 + 9 * q;
      int xg0 = hq & 127, yg0 = hq >> 7;
      const float* px_ = xqb + base0 + 9 * q;
      const float* pf_ = fgb + base0 + 9 * q;
      const float* pb_ = bgb + base0 + 9 * q;
      f4u X0 = *(const f4u*)px_;
      f4u X1 = *(const f4u*)(px_ + 4);
      float X8 = px_[8];
      f4u F0 = *(const f4u*)pf_;
      f4u F1 = *(const f4u*)(pf_ + 4);
      float F8 = pf_[8];
      f4u B0 = *(const f4u*)pb_;
      f4u B1 = *(const f4u*)(pb_ + 4);
      float B8 = pb_[8];
      float XV[9], SF[9], SB[9];
#pragma unroll
      for (int e = 0; e < 9; ++e) {
        int xw = xg0 + e;
        int xp = xw & 127;
        int yp = yg0 + (xw >> 7);
        int inv = (kj0 & (xp == 0)) | (kj2 & (xp == 127)) |
                  (ki0 & (yp == 0)) | (ki2 & (yp == 127));
        float xv = (e < 4) ? X0[e] : ((e < 8) ? X1[e - 4] : X8);
        float fv = (e < 4) ? F0[e] : ((e < 8) ? F1[e - 4] : F8);
        float bv = (e < 4) ? B0[e] : ((e < 8) ? B1[e - 4] : B8);
        XV[e] = inv ? 0.f : xv;
        SF[e] = inv ? 0.f : xv * fv;
        SB[e] = inv ? 0.f : xv - bv;
      }
#pragma unroll
      for (int tr = 0; tr < 3; ++tr) {
        int e = 3 * tr;
        float mf = fmaxf(fmaxf(SF[e], SF[e + 1]), SF[e + 2]);
        float e0 = __expf(SF[e] - mf), e1 = __expf(SF[e + 1] - mf), e2 = __expf(SF[e + 2] - mf);
        float rs = 0.125f / (e0 + e1 + e2);
        resF[e + 0][q] = e0 * rs * XV[e + 0];
        resF[e + 1][q] = e1 * rs * XV[e + 1];
        resF[e + 2][q] = e2 * rs * XV[e + 2];
        float mb = fmaxf(fmaxf(SB[e], SB[e + 1]), SB[e + 2]);
        float g0 = __expf(SB[e] - mb), g1 = __expf(SB[e + 1] - mb), g2 = __expf(SB[e + 2] - mb);
        float rb = 0.125f / (g0 + g1 + g2);
        resB[e + 0][q] = g0 * rb * XV[e + 0];
        resB[e + 1][q] = g1 * rb * XV[e + 1];
        resB[e + 2][q] = g2 * rb * XV[e + 2];
      }
    }
  } else {
    // slow path (~0.2% of threads): kk boundary inside the 36-range
#pragma unroll
    for (int q = 0; q < 4; ++q) {
      float XV[9], SF[9], SB[9];
#pragma unroll
      for (int e = 0; e < 9; ++e) {
        int t = t0 + 9 * q + e;
        int kk = t >> 14;
        int hwp = t & 16383;
        int ki = kk / 3, kj = kk - 3 * ki;
        int sy = (hwp >> 7) + ki - 1;
        int sx = (hwp & 127) + kj - 1;
        float xv = 0.f, sf = 0.f, sb = 0.f;
        if (((unsigned)sy < 128u) && ((unsigned)sx < 128u)) {
          int off = (c << 14) + (sy << 7) + sx;
          xv = xqb[off];
          sf = xv * fgb[off];
          sb = xv - bgb[off];
        }
        XV[e] = xv; SF[e] = sf; SB[e] = sb;
      }
#pragma unroll
      for (int tr = 0; tr < 3; ++tr) {
        int e = 3 * tr;
        float mf = fmaxf(fmaxf(SF[e], SF[e + 1]), SF[e + 2]);
        float e0 = __expf(SF[e] - mf), e1 = __expf(SF[e + 1] - mf), e2 = __expf(SF[e + 2] - mf);
        float rs = 0.125f / (e0 + e1 + e2);
        resF[e + 0][q] = e0 * rs * XV[e + 0];
        resF[e + 1][q] = e1 * rs * XV[e + 1];
        resF[e + 2][q] = e2 * rs * XV[e + 2];
        float mb = fmaxf(fmaxf(SB[e], SB[e + 1]), SB[e + 2]);
        float g0 = __expf(SB[e] - mb), g1 = __expf(SB[e + 1] - mb), g2 = __expf(SB[e + 2] - mb);
        float rb = 0.125f / (g0 + g1 + g2);
        resB[e + 0][q] = g0 * rb * XV[e + 0];
        resB[e + 1][q] = g1 * rb * XV[e + 1];
        resB[e + 2][q] = g2 * rb * XV[e + 2];
      }
    }
  }
#pragma unroll
  for (int m = 0; m < 9; ++m) {
    *(float4*)(cF + ((size_t)m << 20) + n0) =
        make_float4(resF[m][0], resF[m][1], resF[m][2], resF[m][3]);
    *(float4*)(cB + ((size_t)m << 20) + n0) =
        make_float4(resB[m][0], resB[m][1], resB[m][2], resB[m][3]);
  }
}

// ---------------------------------------------------------------------------
// PASS B (8-wide): fold gather. Per thread: 8 consecutive x of one (c2,y).
// Per plane: window [x0-1 .. x0+8] = {lf, m0, m1, rt} (4 loads), static select.
// ---------------------------------------------------------------------------
__global__ __launch_bounds__(256) void passB_k(const float* __restrict__ colsF,
                                               const float* __restrict__ colsB,
                                               float* __restrict__ a, int b0) {
  int bl = blockIdx.x >> 9;
  int idx = ((blockIdx.x & 511) << 8) + threadIdx.x;
  int b = b0 + bl;
  int c2 = idx >> 11;
  int hw0 = (idx << 3) & 16383;
  int y = hw0 >> 7, x0 = hw0 & 127;
  const float* cFb = colsF + ((size_t)bl * 9 << 20);
  const float* cBb = colsB + ((size_t)bl * 9 << 20);
  float af[8], ab[8];
#pragma unroll
  for (int k = 0; k < 8; ++k) { af[k] = 0.f; ab[k] = 0.f; }
#pragma unroll
  for (int i = 0; i < 3; ++i) {
    int yp = y + 1 - i;
    if ((unsigned)yp >= 128u) continue;
#pragma unroll
    for (int j = 0; j < 3; ++j) {
      size_t pb = (((size_t)(c2 * 9 + 3 * i + j)) << 14) + (yp << 7);
      const float* rowF = cFb + pb;
      const float* rowB = cBb + pb;
      float4 m0F = *(const float4*)(rowF + x0);
      float4 m1F = *(const float4*)(rowF + x0 + 4);
      float lfF = (x0 > 0) ? rowF[x0 - 1] : 0.f;
      float rtF = (x0 < 120) ? rowF[x0 + 8] : 0.f;
      float4 m0B = *(const float4*)(rowB + x0);
      float4 m1B = *(const float4*)(rowB + x0 + 4);
      float lfB = (x0 > 0) ? rowB[x0 - 1] : 0.f;
      float rtB = (x0 < 120) ? rowB[x0 + 8] : 0.f;
      float WF[10] = {lfF, m0F.x, m0F.y, m0F.z, m0F.w, m1F.x, m1F.y, m1F.z, m1F.w, rtF};
      float WB[10] = {lfB, m0B.x, m0B.y, m0B.z, m0B.w, m1B.x, m1B.y, m1B.z, m1B.w, rtB};
#pragma unroll
      for (int k = 0; k < 8; ++k) {
        af[k] += WF[k + 2 - j];
        ab[k] += WB[k + 2 - j];
      }
    }
  }
  float* aF = a + (((size_t)b * 128 + c2) << 14) + hw0;
  float* aB = a + (((size_t)b * 128 + 64 + c2) << 14) + hw0;
  *(float4*)(aF)     = make_float4(af[0], af[1], af[2], af[3]);
  *(float4*)(aF + 4) = make_float4(af[4], af[5], af[6], af[7]);
  *(float4*)(aB)     = make_float4(ab[0], ab[1], ab[2], ab[3]);
  *(float4*)(aB + 4) = make_float4(ab[4], ab[5], ab[6], ab[7]);
}

// ---------------------------------------------------------------------------
// Fallback fused attn+fold (verified) — used only if ws too small.
// ---------------------------------------------------------------------------
__device__ __forceinline__ void triel(const float* __restrict__ xqb,
                                      const float* __restrict__ fgb,
                                      const float* __restrict__ bgb,
                                      int fe, float& xv, float& sf, float& sb) {
  int u = fe >> 14;
  int hwp = fe & 16383;
  int c = u / 9;
  int kk = u - c * 9;
  int ki = kk / 3;
  int kj = kk - ki * 3;
  int sy = (hwp >> 7) + ki - 1;
  int sx = (hwp & 127) + kj - 1;
  if (((unsigned)sy < 128u) && ((unsigned)sx < 128u)) {
    int off = (c << 14) + (sy << 7) + sx;
    float xv_ = xqb[off];
    xv = xv_;
    sf = xv_ * fgb[off];
    sb = xv_ - bgb[off];
  } else {
    xv = 0.f; sf = 0.f; sb = 0.f;
  }
}

__global__ __launch_bounds__(256) void attnfold_k(const float* __restrict__ xq,
                                                  const float* __restrict__ fgp,
                                                  const float* __restrict__ bgp,
                                                  float* __restrict__ a) {
  int gidx = blockIdx.x * 256 + threadIdx.x;
  int hw = gidx & 16383;
  int bc = gidx >> 14;
  int c2 = bc & 63;
  int b = bc >> 6;
  int y = hw >> 7, x = hw & 127;
  const float* xqb = xq + (b << 20);
  const float* fgb = fgp + (b << 20);
  const float* bgb = bgp + (b << 20);
  float accf = 0.f, accb = 0.f;
#pragma unroll
  for (int i = 0; i < 3; ++i) {
    int yp = y + 1 - i;
    if ((unsigned)yp >= 128u) continue;
#pragma unroll
    for (int j = 0; j < 3; ++j) {
      int xp = x + 1 - j;
      if ((unsigned)xp >= 128u) continue;
      int g = ((c2 * 9 + i * 3 + j) << 14) + (yp << 7) + xp;
      int m = g >> 20;
      int n = g & 1048575;
      int f = n * 9 + m;
      int q = f % 3;
      int f0 = f - q;
      float xv0, sf0, sb0, xv1, sf1, sb1, xv2, sf2, sb2;
      triel(xqb, fgb, bgb, f0,     xv0, sf0, sb0);
      triel(xqb, fgb, bgb, f0 + 1, xv1, sf1, sb1);
      triel(xqb, fgb, bgb, f0 + 2, xv2, sf2, sb2);
      float xsel = (q == 0) ? xv0 : ((q == 1) ? xv1 : xv2);
      float mf = fmaxf(fmaxf(sf0, sf1), sf2);
      float ef0 = __expf(sf0 - mf), ef1 = __expf(sf1 - mf), ef2 = __expf(sf2 - mf);
      float self_f = (q == 0) ? ef0 : ((q == 1) ? ef1 : ef2);
      accf += self_f / (ef0 + ef1 + ef2) * xsel;
      float mb = fmaxf(fmaxf(sb0, sb1), sb2);
      float eb0 = __expf(sb0 - mb), eb1 = __expf(sb1 - mb), eb2 = __expf(sb2 - mb);
      float self_b = (q == 0) ? eb0 : ((q == 1) ? eb1 : eb2);
      accb += self_b / (eb0 + eb1 + eb2) * xsel;
    }
  }
  a[((b * 128 + c2) << 14) + hw] = accf * 0.125f;
  a[((b * 128 + 64 + c2) << 14) + hw] = accb * 0.125f;
}

// ---------------------------------------------------------------------------
extern "C" void kernel_launch(void* const* d_in, const int* in_sizes, int n_in,
                              void* d_out, int out_size, void* d_ws, size_t ws_size,
                              hipStream_t stream) {
  (void)in_sizes; (void)n_in; (void)out_size;
  const float* x      = (const float*)d_in[0];
  const float* fg     = (const float*)d_in[1];
  const float* bg     = (const float*)d_in[2];
  const float* w_x    = (const float*)d_in[3];
  const float* bias_x = (const float*)d_in[4];
  const float* w_f    = (const float*)d_in[5];
  const float* bias_f = (const float*)d_in[6];
  const float* w_b    = (const float*)d_in[7];
  const float* bias_b = (const float*)d_in[8];
  const float* w1     = (const float*)d_in[9];
  const float* b1     = (const float*)d_in[10];
  const float* g1     = (const float*)d_in[11];
  const float* be1    = (const float*)d_in[12];
  const float* w2     = (const float*)d_in[13];
  const float* b2     = (const float*)d_in[14];
  const float* w3     = (const float*)d_in[15];
  const float* b3     = (const float*)d_in[16];
  const float* g2     = (const float*)d_in[17];
  const float* be2    = (const float*)d_in[18];
  const float* w4     = (const float*)d_in[19];
  const float* b4     = (const float*)d_in[20];
  float* out = (float*)d_out;
  float* ws  = (float*)d_ws;

  const size_t NCHWf = (size_t)NB * 64 * HWSZ;  // 4,194,304 floats
  // 256-float front pad: passA fast-path windows can underrun the first
  // plane by up to ~130 floats (masked lanes) — keep reads in-bounds.
  float* base = ws + 256;
  float* xq  = base;
  float* fgp = base + NCHWf;
  float* bgp = base + 2 * NCHWf;
  float* a   = base + 3 * NCHWf;                // 2*NCHWf floats
  float* colsbase = base + 5 * NCHWf;
  // dead-buffer reuse for the tail chain:
  float* t1 = fgp;   // fgp dead after passA
  float* y2 = xq;    // xq dead after passA
  float* t2 = bgp;   // bgp dead after passA

  dim3 blk(256);
  pw_k<<<NB * 256, blk, 0, stream>>>(x,  w_x, bias_x, xq);
  pw_k<<<NB * 256, blk, 0, stream>>>(fg, w_f, bias_f, fgp);
  pw_k<<<NB * 256, blk, 0, stream>>>(bg, w_b, bias_b, bgp);

  // cols workspace: per batch, colsF + colsB = 18M floats = 75.5 MB.
  const size_t usedB = (5 * NCHWf + 512) * 4;
  const size_t perBatchColsF = (size_t)18 << 20;  // floats
  size_t availF = (ws_size > usedB) ? (ws_size - usedB) / 4 : 0;
  int fit = (int)(availF / perBatchColsF);
  if (fit > NB) fit = NB;

  if (fit >= 1) {
    float* colsF = colsbase;
    float* colsB = colsbase + ((size_t)fit * 9 << 20);
    for (int b0 = 0; b0 < NB; b0 += fit) {
      int nb = (NB - b0 < fit) ? (NB - b0) : fit;
      passA_k<<<nb * 1024, blk, 0, stream>>>(xq, fgp, bgp, colsF, colsB, b0);
      passB_k<<<nb * 512, blk, 0, stream>>>(colsF, colsB, a, b0);
    }
  } else {
    attnfold_k<<<NB * 64 * HWSZ / 256, blk, 0, stream>>>(xq, fgp, bgp, a);
  }

  gconv1_k<<<NB * 1024, blk, 0, stream>>>(a, w1, b1, g1, be1, t1);
  pw_k<<<NB * 256, blk, 0, stream>>>(t1, w2, b2, y2);
  dconv_k<<<NB * 1024, blk, 0, stream>>>(y2, w3, b3, g2, be2, t2);
  pw_k<<<NB * 256, blk, 0, stream>>>(t2, w4, b4, out);
}

// Round 6
// 279.541 us; speedup vs baseline: 3.8965x; 1.3903x over previous
//
#include <hip/hip_runtime.h>

// Problem constants: B=4, C_IN=C=64, H=W=128, K=3, SCALE=0.125, EPS=1e-5
#define NB 4
#define HWSZ 16384   // 128*128

// 16B vector with only 4B alignment guarantee (gfx9+ supports unaligned dwordx4)
typedef float f4u __attribute__((ext_vector_type(4), aligned(4)));
// 16B-aligned ext vector for nontemporal ops
typedef float f4a __attribute__((ext_vector_type(4)));

// ---------------------------------------------------------------------------
// pw body: 1x1 conv (64 -> 64) + bias. 1024 blocks per op.
// Block: 256 thr = 64 px4-lanes x 4 og; covers 256 px x 16 o.
// ---------------------------------------------------------------------------
__device__ __forceinline__ void pw_body(int bid, int tid,
                                        const float* __restrict__ in,
                                        const float* __restrict__ w,
                                        const float* __restrict__ bias,
                                        float* __restrict__ out,
                                        float* wls) {
  int b = bid >> 8;
  int r = bid & 255;
  int oc = r >> 6;          // 0..3: which 16-o chunk
  int pc = r & 63;          // 256-px chunk
  int px4 = tid & 63;
  int og = tid >> 6;        // wave index: uniform within wave
  int px = (pc << 8) + (px4 << 2);
#pragma unroll
  for (int it = 0; it < 4; ++it)
    wls[(it << 8) + tid] = w[(oc << 10) + (it << 8) + tid];
  __syncthreads();
  int ob = (oc << 4) + (og << 2);
  float4 acc[4];
#pragma unroll
  for (int j = 0; j < 4; ++j) {
    float bv = bias[ob + j];
    acc[j] = make_float4(bv, bv, bv, bv);
  }
  const float* ip = in + (((size_t)b << 6) << 14) + px;
  const float* wp = wls + ((og << 2) << 6);
#pragma unroll 4
  for (int cc = 0; cc < 64; ++cc) {
    float4 xv = *(const float4*)(ip + ((size_t)cc << 14));
#pragma unroll
    for (int j = 0; j < 4; ++j) {
      float wv = wp[(j << 6) + cc];
      acc[j].x = fmaf(wv, xv.x, acc[j].x);
      acc[j].y = fmaf(wv, xv.y, acc[j].y);
      acc[j].z = fmaf(wv, xv.z, acc[j].z);
      acc[j].w = fmaf(wv, xv.w, acc[j].w);
    }
  }
#pragma unroll
  for (int j = 0; j < 4; ++j)
    *(float4*)(out + (((size_t)(b << 6) + ob + j) << 14) + px) = acc[j];
}

__global__ __launch_bounds__(256) void pw_k(const float* __restrict__ in,
                                            const float* __restrict__ w,
                                            const float* __restrict__ bias,
                                            float* __restrict__ out) {
  __shared__ float wls[16 * 64];
  pw_body(blockIdx.x, threadIdx.x, in, w, bias, out, wls);
}

// three independent 1x1 convs in one dispatch (front of the graph)
__global__ __launch_bounds__(256) void pw3_k(const float* __restrict__ in0,
                                             const float* __restrict__ in1,
                                             const float* __restrict__ in2,
                                             const float* __restrict__ w0,
                                             const float* __restrict__ w1,
                                             const float* __restrict__ w2,
                                             const float* __restrict__ bi0,
                                             const float* __restrict__ bi1,
                                             const float* __restrict__ bi2,
                                             float* __restrict__ o0,
                                             float* __restrict__ o1,
                                             float* __restrict__ o2) {
  __shared__ float wls[16 * 64];
  int which = blockIdx.x >> 10;
  int bid = blockIdx.x & 1023;
  const float* in = (which == 0) ? in0 : (which == 1) ? in1 : in2;
  const float* w  = (which == 0) ? w0  : (which == 1) ? w1  : w2;
  const float* bi = (which == 0) ? bi0 : (which == 1) ? bi1 : bi2;
  float* out      = (which == 0) ? o0  : (which == 1) ? o1  : o2;
  pw_body(bid, threadIdx.x, in, w, bi, out, wls);
}

// ---------------------------------------------------------------------------
// gconv1_k: grouped 3x3 (o reads concat ch 2o,2o+1) + b1 + BN + ReLU -> t1
// ---------------------------------------------------------------------------
__global__ __launch_bounds__(256) void gconv1_k(const float* __restrict__ a,
                                                const float* __restrict__ w1,
                                                const float* __restrict__ b1,
                                                const float* __restrict__ g1,
                                                const float* __restrict__ be1,
                                                float* __restrict__ t1) {
  int bid = blockIdx.x;
  int b = bid >> 10;
  int r = bid & 1023;
  int o = r >> 4;
  int rc = r & 15;
  int tid = threadIdx.x;
  int px4 = tid & 31;
  int ry = tid >> 5;
  int y = (rc << 3) + ry;
  int x0 = px4 << 2;
  float bv = b1[o];
  float4 acc = make_float4(bv, bv, bv, bv);
#pragma unroll
  for (int ic = 0; ic < 2; ++ic) {
    const float* ap = a + ((size_t)(b * 128 + 2 * o + ic) << 14);
    const float* wr0 = w1 + o * 18 + ic * 9;
#pragma unroll
    for (int dy = 0; dy < 3; ++dy) {
      int yy = y + dy - 1;
      if ((unsigned)yy >= 128u) continue;
      const float* row = ap + (yy << 7);
      float4 mid = *(const float4*)(row + x0);
      float lf = (px4 > 0) ? row[x0 - 1] : 0.f;
      float rt = (px4 < 31) ? row[x0 + 4] : 0.f;
      float wa = wr0[dy * 3 + 0], wb = wr0[dy * 3 + 1], wc = wr0[dy * 3 + 2];
      acc.x += wa * lf    + wb * mid.x + wc * mid.y;
      acc.y += wa * mid.x + wb * mid.y + wc * mid.z;
      acc.z += wa * mid.y + wb * mid.z + wc * mid.w;
      acc.w += wa * mid.z + wb * mid.w + wc * rt;
    }
  }
  const float invs = 0.9999950000374997f;  // 1/sqrt(1+1e-5)
  float s = g1[o] * invs, be = be1[o];
  acc.x = fmaxf(acc.x * s + be, 0.f);
  acc.y = fmaxf(acc.y * s + be, 0.f);
  acc.z = fmaxf(acc.z * s + be, 0.f);
  acc.w = fmaxf(acc.w * s + be, 0.f);
  *(float4*)(t1 + (((size_t)(b << 6) + o) << 14) + (y << 7) + x0) = acc;
}

// ---------------------------------------------------------------------------
// dconv_k: depthwise 3x3 + b3 + BN + ReLU -> t2
// ---------------------------------------------------------------------------
__global__ __launch_bounds__(256) void dconv_k(const float* __restrict__ y2,
                                               const float* __restrict__ w3,
                                               const float* __restrict__ b3,
                                               const float* __restrict__ g2,
                                               const float* __restrict__ be2,
                                               float* __restrict__ t2) {
  int bid = blockIdx.x;
  int b = bid >> 10;
  int r = bid & 1023;
  int o = r >> 4;
  int rc = r & 15;
  int tid = threadIdx.x;
  int px4 = tid & 31;
  int ry = tid >> 5;
  int y = (rc << 3) + ry;
  int x0 = px4 << 2;
  float bv = b3[o];
  float4 acc = make_float4(bv, bv, bv, bv);
  const float* ap = y2 + (((size_t)(b << 6) + o) << 14);
  const float* wr0 = w3 + o * 9;
#pragma unroll
  for (int dy = 0; dy < 3; ++dy) {
    int yy = y + dy - 1;
    if ((unsigned)yy >= 128u) continue;
    const float* row = ap + (yy << 7);
    float4 mid = *(const float4*)(row + x0);
    float lf = (px4 > 0) ? row[x0 - 1] : 0.f;
    float rt = (px4 < 31) ? row[x0 + 4] : 0.f;
    float wa = wr0[dy * 3 + 0], wb = wr0[dy * 3 + 1], wc = wr0[dy * 3 + 2];
    acc.x += wa * lf    + wb * mid.x + wc * mid.y;
    acc.y += wa * mid.x + wb * mid.y + wc * mid.z;
    acc.z += wa * mid.y + wb * mid.z + wc * mid.w;
    acc.w += wa * mid.z + wb * mid.w + wc * rt;
  }
  const float invs = 0.9999950000374997f;
  float s = g2[o] * invs, be = be2[o];
  acc.x = fmaxf(acc.x * s + be, 0.f);
  acc.y = fmaxf(acc.y * s + be, 0.f);
  acc.z = fmaxf(acc.z * s + be, 0.f);
  acc.w = fmaxf(acc.w * s + be, 0.f);
  *(float4*)(t2 + (((size_t)(b << 6) + o) << 14) + (y << 7) + x0) = acc;
}

// ---------------------------------------------------------------------------
// PASS A (4-wide, XCD-swizzled, nt stores): thread handles n0..n0+3 (one
// channel c = n0>>14). Within one kk region, addr is linear in t, so the 36
// reads per array are contiguous; boundary elements masked in VALU.
// XCD swizzle: v = (vb&7)*128 + vb>>3 puts each channel's 16 blocks on ONE
// XCD (8 channels / 1.5 MB per XCD chunk << 4 MB L2) so the x9 positional
// re-read becomes L2 hits. cols stores are nontemporal (written once, read
// once in passB) to keep L2 free for the input planes.
// ---------------------------------------------------------------------------
__global__ __launch_bounds__(256) void passA_k(const float* __restrict__ xq,
                                               const float* __restrict__ fgp,
                                               const float* __restrict__ bgp,
                                               float* __restrict__ colsF,
                                               float* __restrict__ colsB,
                                               int b0) {
  int bl = blockIdx.x >> 10;
  int vb = blockIdx.x & 1023;
  int v = ((vb & 7) << 7) + (vb >> 3);           // XCD-chunked swizzle
  int n0 = ((v << 8) + threadIdx.x) << 2;
  int b = b0 + bl;
  const float* xqb = xq + ((size_t)b << 20);
  const float* fgb = fgp + ((size_t)b << 20);
  const float* bgb = bgp + ((size_t)b << 20);
  float* cF = colsF + ((size_t)bl * 9 << 20);
  float* cB = colsB + ((size_t)bl * 9 << 20);
  int c = n0 >> 14;
  int l0 = n0 & 16383;
  int t0 = 9 * l0;
  int r0 = t0 & 16383;
  int kk0 = t0 >> 14;
  float resF[9][4], resB[9][4];

  if (r0 <= 16348) {
    // fast path: whole 36-range in one kk region
    int ki = kk0 / 3, kj = kk0 - 3 * ki;
    int base0 = (c << 14) + r0 + ((ki - 1) << 7) + (kj - 1);
    int kj0 = (kj == 0), kj2 = (kj == 2), ki0 = (ki == 0), ki2 = (ki == 2);
#pragma unroll
    for (int q = 0; q < 4; ++q) {
      int hq = r0 + 9 * q;
      int xg0 = hq & 127, yg0 = hq >> 7;
      const float* px_ = xqb + base0 + 9 * q;
      const float* pf_ = fgb + base0 + 9 * q;
      const float* pb_ = bgb + base0 + 9 * q;
      f4u X0 = *(const f4u*)px_;
      f4u X1 = *(const f4u*)(px_ + 4);
      float X8 = px_[8];
      f4u F0 = *(const f4u*)pf_;
      f4u F1 = *(const f4u*)(pf_ + 4);
      float F8 = pf_[8];
      f4u B0 = *(const f4u*)pb_;
      f4u B1 = *(const f4u*)(pb_ + 4);
      float B8 = pb_[8];
      float XV[9], SF[9], SB[9];
#pragma unroll
      for (int e = 0; e < 9; ++e) {
        int xw = xg0 + e;
        int xp = xw & 127;
        int yp = yg0 + (xw >> 7);
        int inv = (kj0 & (xp == 0)) | (kj2 & (xp == 127)) |
                  (ki0 & (yp == 0)) | (ki2 & (yp == 127));
        float xv = (e < 4) ? X0[e] : ((e < 8) ? X1[e - 4] : X8);
        float fv = (e < 4) ? F0[e] : ((e < 8) ? F1[e - 4] : F8);
        float bv = (e < 4) ? B0[e] : ((e < 8) ? B1[e - 4] : B8);
        XV[e] = inv ? 0.f : xv;
        SF[e] = inv ? 0.f : xv * fv;
        SB[e] = inv ? 0.f : xv - bv;
      }
#pragma unroll
      for (int tr = 0; tr < 3; ++tr) {
        int e = 3 * tr;
        float mf = fmaxf(fmaxf(SF[e], SF[e + 1]), SF[e + 2]);
        float e0 = __expf(SF[e] - mf), e1 = __expf(SF[e + 1] - mf), e2 = __expf(SF[e + 2] - mf);
        float rs = 0.125f / (e0 + e1 + e2);
        resF[e + 0][q] = e0 * rs * XV[e + 0];
        resF[e + 1][q] = e1 * rs * XV[e + 1];
        resF[e + 2][q] = e2 * rs * XV[e + 2];
        float mb = fmaxf(fmaxf(SB[e], SB[e + 1]), SB[e + 2]);
        float g0 = __expf(SB[e] - mb), g1 = __expf(SB[e + 1] - mb), g2 = __expf(SB[e + 2] - mb);
        float rb = 0.125f / (g0 + g1 + g2);
        resB[e + 0][q] = g0 * rb * XV[e + 0];
        resB[e + 1][q] = g1 * rb * XV[e + 1];
        resB[e + 2][q] = g2 * rb * XV[e + 2];
      }
    }
  } else {
    // slow path (~0.2% of threads): kk boundary inside the 36-range
#pragma unroll
    for (int q = 0; q < 4; ++q) {
      float XV[9], SF[9], SB[9];
#pragma unroll
      for (int e = 0; e < 9; ++e) {
        int t = t0 + 9 * q + e;
        int kk = t >> 14;
        int hwp = t & 16383;
        int ki = kk / 3, kj = kk - 3 * ki;
        int sy = (hwp >> 7) + ki - 1;
        int sx = (hwp & 127) + kj - 1;
        float xv = 0.f, sf = 0.f, sb = 0.f;
        if (((unsigned)sy < 128u) && ((unsigned)sx < 128u)) {
          int off = (c << 14) + (sy << 7) + sx;
          xv = xqb[off];
          sf = xv * fgb[off];
          sb = xv - bgb[off];
        }
        XV[e] = xv; SF[e] = sf; SB[e] = sb;
      }
#pragma unroll
      for (int tr = 0; tr < 3; ++tr) {
        int e = 3 * tr;
        float mf = fmaxf(fmaxf(SF[e], SF[e + 1]), SF[e + 2]);
        float e0 = __expf(SF[e] - mf), e1 = __expf(SF[e + 1] - mf), e2 = __expf(SF[e + 2] - mf);
        float rs = 0.125f / (e0 + e1 + e2);
        resF[e + 0][q] = e0 * rs * XV[e + 0];
        resF[e + 1][q] = e1 * rs * XV[e + 1];
        resF[e + 2][q] = e2 * rs * XV[e + 2];
        float mb = fmaxf(fmaxf(SB[e], SB[e + 1]), SB[e + 2]);
        float g0 = __expf(SB[e] - mb), g1 = __expf(SB[e + 1] - mb), g2 = __expf(SB[e + 2] - mb);
        float rb = 0.125f / (g0 + g1 + g2);
        resB[e + 0][q] = g0 * rb * XV[e + 0];
        resB[e + 1][q] = g1 * rb * XV[e + 1];
        resB[e + 2][q] = g2 * rb * XV[e + 2];
      }
    }
  }
#pragma unroll
  for (int m = 0; m < 9; ++m) {
    f4a vF = {resF[m][0], resF[m][1], resF[m][2], resF[m][3]};
    f4a vB = {resB[m][0], resB[m][1], resB[m][2], resB[m][3]};
    __builtin_nontemporal_store(vF, (f4a*)(cF + ((size_t)m << 20) + n0));
    __builtin_nontemporal_store(vB, (f4a*)(cB + ((size_t)m << 20) + n0));
  }
}

// ---------------------------------------------------------------------------
// PASS B (8-wide, nt loads): fold gather. Per thread: 8 consecutive x of one
// (c2,y). Per plane: window {lf, m0, m1, rt}, static select. cols read once.
// ---------------------------------------------------------------------------
__global__ __launch_bounds__(256) void passB_k(const float* __restrict__ colsF,
                                               const float* __restrict__ colsB,
                                               float* __restrict__ a, int b0) {
  int bl = blockIdx.x >> 9;
  int idx = ((blockIdx.x & 511) << 8) + threadIdx.x;
  int b = b0 + bl;
  int c2 = idx >> 11;
  int hw0 = (idx << 3) & 16383;
  int y = hw0 >> 7, x0 = hw0 & 127;
  const float* cFb = colsF + ((size_t)bl * 9 << 20);
  const float* cBb = colsB + ((size_t)bl * 9 << 20);
  float af[8], ab[8];
#pragma unroll
  for (int k = 0; k < 8; ++k) { af[k] = 0.f; ab[k] = 0.f; }
#pragma unroll
  for (int i = 0; i < 3; ++i) {
    int yp = y + 1 - i;
    if ((unsigned)yp >= 128u) continue;
#pragma unroll
    for (int j = 0; j < 3; ++j) {
      size_t pb = (((size_t)(c2 * 9 + 3 * i + j)) << 14) + (yp << 7);
      const float* rowF = cFb + pb;
      const float* rowB = cBb + pb;
      f4a m0F = __builtin_nontemporal_load((const f4a*)(rowF + x0));
      f4a m1F = __builtin_nontemporal_load((const f4a*)(rowF + x0 + 4));
      float lfF = (x0 > 0) ? rowF[x0 - 1] : 0.f;
      float rtF = (x0 < 120) ? rowF[x0 + 8] : 0.f;
      f4a m0B = __builtin_nontemporal_load((const f4a*)(rowB + x0));
      f4a m1B = __builtin_nontemporal_load((const f4a*)(rowB + x0 + 4));
      float lfB = (x0 > 0) ? rowB[x0 - 1] : 0.f;
      float rtB = (x0 < 120) ? rowB[x0 + 8] : 0.f;
      float WF[10] = {lfF, m0F[0], m0F[1], m0F[2], m0F[3], m1F[0], m1F[1], m1F[2], m1F[3], rtF};
      float WB[10] = {lfB, m0B[0], m0B[1], m0B[2], m0B[3], m1B[0], m1B[1], m1B[2], m1B[3], rtB};
#pragma unroll
      for (int k = 0; k < 8; ++k) {
        af[k] += WF[k + 2 - j];
        ab[k] += WB[k + 2 - j];
      }
    }
  }
  float* aF = a + (((size_t)b * 128 + c2) << 14) + hw0;
  float* aB = a + (((size_t)b * 128 + 64 + c2) << 14) + hw0;
  *(float4*)(aF)     = make_float4(af[0], af[1], af[2], af[3]);
  *(float4*)(aF + 4) = make_float4(af[4], af[5], af[6], af[7]);
  *(float4*)(aB)     = make_float4(ab[0], ab[1], ab[2], ab[3]);
  *(float4*)(aB + 4) = make_float4(ab[4], ab[5], ab[6], ab[7]);
}

// ---------------------------------------------------------------------------
// Fallback fused attn+fold (verified) — used only if ws too small.
// ---------------------------------------------------------------------------
__device__ __forceinline__ void triel(const float* __restrict__ xqb,
                                      const float* __restrict__ fgb,
                                      const float* __restrict__ bgb,
                                      int fe, float& xv, float& sf, float& sb) {
  int u = fe >> 14;
  int hwp = fe & 16383;
  int c = u / 9;
  int kk = u - c * 9;
  int ki = kk / 3;
  int kj = kk - ki * 3;
  int sy = (hwp >> 7) + ki - 1;
  int sx = (hwp & 127) + kj - 1;
  if (((unsigned)sy < 128u) && ((unsigned)sx < 128u)) {
    int off = (c << 14) + (sy << 7) + sx;
    float xv_ = xqb[off];
    xv = xv_;
    sf = xv_ * fgb[off];
    sb = xv_ - bgb[off];
  } else {
    xv = 0.f; sf = 0.f; sb = 0.f;
  }
}

__global__ __launch_bounds__(256) void attnfold_k(const float* __restrict__ xq,
                                                  const float* __restrict__ fgp,
                                                  const float* __restrict__ bgp,
                                                  float* __restrict__ a) {
  int gidx = blockIdx.x * 256 + threadIdx.x;
  int hw = gidx & 16383;
  int bc = gidx >> 14;
  int c2 = bc & 63;
  int b = bc >> 6;
  int y = hw >> 7, x = hw & 127;
  const float* xqb = xq + (b << 20);
  const float* fgb = fgp + (b << 20);
  const float* bgb = bgp + (b << 20);
  float accf = 0.f, accb = 0.f;
#pragma unroll
  for (int i = 0; i < 3; ++i) {
    int yp = y + 1 - i;
    if ((unsigned)yp >= 128u) continue;
#pragma unroll
    for (int j = 0; j < 3; ++j) {
      int xp = x + 1 - j;
      if ((unsigned)xp >= 128u) continue;
      int g = ((c2 * 9 + i * 3 + j) << 14) + (yp << 7) + xp;
      int m = g >> 20;
      int n = g & 1048575;
      int f = n * 9 + m;
      int q = f % 3;
      int f0 = f - q;
      float xv0, sf0, sb0, xv1, sf1, sb1, xv2, sf2, sb2;
      triel(xqb, fgb, bgb, f0,     xv0, sf0, sb0);
      triel(xqb, fgb, bgb, f0 + 1, xv1, sf1, sb1);
      triel(xqb, fgb, bgb, f0 + 2, xv2, sf2, sb2);
      float xsel = (q == 0) ? xv0 : ((q == 1) ? xv1 : xv2);
      float mf = fmaxf(fmaxf(sf0, sf1), sf2);
      float ef0 = __expf(sf0 - mf), ef1 = __expf(sf1 - mf), ef2 = __expf(sf2 - mf);
      float self_f = (q == 0) ? ef0 : ((q == 1) ? ef1 : ef2);
      accf += self_f / (ef0 + ef1 + ef2) * xsel;
      float mb = fmaxf(fmaxf(sb0, sb1), sb2);
      float eb0 = __expf(sb0 - mb), eb1 = __expf(sb1 - mb), eb2 = __expf(sb2 - mb);
      float self_b = (q == 0) ? eb0 : ((q == 1) ? eb1 : eb2);
      accb += self_b / (eb0 + eb1 + eb2) * xsel;
    }
  }
  a[((b * 128 + c2) << 14) + hw] = accf * 0.125f;
  a[((b * 128 + 64 + c2) << 14) + hw] = accb * 0.125f;
}

// ---------------------------------------------------------------------------
extern "C" void kernel_launch(void* const* d_in, const int* in_sizes, int n_in,
                              void* d_out, int out_size, void* d_ws, size_t ws_size,
                              hipStream_t stream) {
  (void)in_sizes; (void)n_in; (void)out_size;
  const float* x      = (const float*)d_in[0];
  const float* fg     = (const float*)d_in[1];
  const float* bg     = (const float*)d_in[2];
  const float* w_x    = (const float*)d_in[3];
  const float* bias_x = (const float*)d_in[4];
  const float* w_f    = (const float*)d_in[5];
  const float* bias_f = (const float*)d_in[6];
  const float* w_b    = (const float*)d_in[7];
  const float* bias_b = (const float*)d_in[8];
  const float* w1     = (const float*)d_in[9];
  const float* b1     = (const float*)d_in[10];
  const float* g1     = (const float*)d_in[11];
  const float* be1    = (const float*)d_in[12];
  const float* w2     = (const float*)d_in[13];
  const float* b2     = (const float*)d_in[14];
  const float* w3     = (const float*)d_in[15];
  const float* b3     = (const float*)d_in[16];
  const float* g2     = (const float*)d_in[17];
  const float* be2    = (const float*)d_in[18];
  const float* w4     = (const float*)d_in[19];
  const float* b4     = (const float*)d_in[20];
  float* out = (float*)d_out;
  float* ws  = (float*)d_ws;

  const size_t NCHWf = (size_t)NB * 64 * HWSZ;  // 4,194,304 floats
  // 256-float front pad: passA fast-path windows can underrun the first
  // plane by up to ~130 floats (masked lanes) — keep reads in-bounds.
  float* base = ws + 256;
  float* xq  = base;
  float* fgp = base + NCHWf;
  float* bgp = base + 2 * NCHWf;
  float* a   = base + 3 * NCHWf;                // 2*NCHWf floats
  float* colsbase = base + 5 * NCHWf;
  // dead-buffer reuse for the tail chain:
  float* t1 = fgp;   // fgp dead after passA
  float* y2 = xq;    // xq dead after passA
  float* t2 = bgp;   // bgp dead after passA

  dim3 blk(256);
  pw3_k<<<3 * NB * 256, blk, 0, stream>>>(x, fg, bg, w_x, w_f, w_b,
                                          bias_x, bias_f, bias_b, xq, fgp, bgp);

  // cols workspace: per batch, colsF + colsB = 18M floats = 75.5 MB.
  const size_t usedB = (5 * NCHWf + 512) * 4;
  const size_t perBatchColsF = (size_t)18 << 20;  // floats
  size_t availF = (ws_size > usedB) ? (ws_size - usedB) / 4 : 0;
  int fit = (int)(availF / perBatchColsF);
  if (fit > NB) fit = NB;

  if (fit >= 1) {
    float* colsF = colsbase;
    float* colsB = colsbase + ((size_t)fit * 9 << 20);
    for (int b0 = 0; b0 < NB; b0 += fit) {
      int nb = (NB - b0 < fit) ? (NB - b0) : fit;
      passA_k<<<nb * 1024, blk, 0, stream>>>(xq, fgp, bgp, colsF, colsB, b0);
      passB_k<<<nb * 512, blk, 0, stream>>>(colsF, colsB, a, b0);
    }
  } else {
    attnfold_k<<<NB * 64 * HWSZ / 256, blk, 0, stream>>>(xq, fgp, bgp, a);
  }

  gconv1_k<<<NB * 1024, blk, 0, stream>>>(a, w1, b1, g1, be1, t1);
  pw_k<<<NB * 256, blk, 0, stream>>>(t1, w2, b2, y2);
  dconv_k<<<NB * 1024, blk, 0, stream>>>(y2, w3, b3, g2, be2, t2);
  pw_k<<<NB * 256, blk, 0, stream>>>(t2, w4, b4, out);
}

// Round 7
// 219.858 us; speedup vs baseline: 4.9542x; 1.2715x over previous
//
#include <hip/hip_runtime.h>

// Problem constants: B=4, C_IN=C=64, H=W=128, K=3, SCALE=0.125, EPS=1e-5
#define NB 4
#define HWSZ 16384   // 128*128

// 16B vector with only 4B alignment guarantee (gfx9+ supports unaligned dwordx4)
typedef float f4u __attribute__((ext_vector_type(4), aligned(4)));
// fp16 vectors for the cols tensor (stored fp16, computed fp32)
typedef _Float16 h4 __attribute__((ext_vector_type(4)));
typedef _Float16 h8 __attribute__((ext_vector_type(8)));

// ---------------------------------------------------------------------------
// pw body: 1x1 conv (64 -> 64) + bias. 1024 blocks per op.
// Block: 256 thr = 64 px4-lanes x 4 og; covers 256 px x 16 o.
// ---------------------------------------------------------------------------
__device__ __forceinline__ void pw_body(int bid, int tid,
                                        const float* __restrict__ in,
                                        const float* __restrict__ w,
                                        const float* __restrict__ bias,
                                        float* __restrict__ out,
                                        float* wls) {
  int b = bid >> 8;
  int r = bid & 255;
  int oc = r >> 6;          // 0..3: which 16-o chunk
  int pc = r & 63;          // 256-px chunk
  int px4 = tid & 63;
  int og = tid >> 6;        // wave index: uniform within wave
  int px = (pc << 8) + (px4 << 2);
#pragma unroll
  for (int it = 0; it < 4; ++it)
    wls[(it << 8) + tid] = w[(oc << 10) + (it << 8) + tid];
  __syncthreads();
  int ob = (oc << 4) + (og << 2);
  float4 acc[4];
#pragma unroll
  for (int j = 0; j < 4; ++j) {
    float bv = bias[ob + j];
    acc[j] = make_float4(bv, bv, bv, bv);
  }
  const float* ip = in + (((size_t)b << 6) << 14) + px;
  const float* wp = wls + ((og << 2) << 6);
#pragma unroll 4
  for (int cc = 0; cc < 64; ++cc) {
    float4 xv = *(const float4*)(ip + ((size_t)cc << 14));
#pragma unroll
    for (int j = 0; j < 4; ++j) {
      float wv = wp[(j << 6) + cc];
      acc[j].x = fmaf(wv, xv.x, acc[j].x);
      acc[j].y = fmaf(wv, xv.y, acc[j].y);
      acc[j].z = fmaf(wv, xv.z, acc[j].z);
      acc[j].w = fmaf(wv, xv.w, acc[j].w);
    }
  }
#pragma unroll
  for (int j = 0; j < 4; ++j)
    *(float4*)(out + (((size_t)(b << 6) + ob + j) << 14) + px) = acc[j];
}

__global__ __launch_bounds__(256) void pw_k(const float* __restrict__ in,
                                            const float* __restrict__ w,
                                            const float* __restrict__ bias,
                                            float* __restrict__ out) {
  __shared__ float wls[16 * 64];
  pw_body(blockIdx.x, threadIdx.x, in, w, bias, out, wls);
}

// three independent 1x1 convs in one dispatch (front of the graph)
__global__ __launch_bounds__(256) void pw3_k(const float* __restrict__ in0,
                                             const float* __restrict__ in1,
                                             const float* __restrict__ in2,
                                             const float* __restrict__ w0,
                                             const float* __restrict__ w1,
                                             const float* __restrict__ w2,
                                             const float* __restrict__ bi0,
                                             const float* __restrict__ bi1,
                                             const float* __restrict__ bi2,
                                             float* __restrict__ o0,
                                             float* __restrict__ o1,
                                             float* __restrict__ o2) {
  __shared__ float wls[16 * 64];
  int which = blockIdx.x >> 10;
  int bid = blockIdx.x & 1023;
  const float* in = (which == 0) ? in0 : (which == 1) ? in1 : in2;
  const float* w  = (which == 0) ? w0  : (which == 1) ? w1  : w2;
  const float* bi = (which == 0) ? bi0 : (which == 1) ? bi1 : bi2;
  float* out      = (which == 0) ? o0  : (which == 1) ? o1  : o2;
  pw_body(bid, threadIdx.x, in, w, bi, out, wls);
}

// ---------------------------------------------------------------------------
// gconv1_k: grouped 3x3 (o reads concat ch 2o,2o+1) + b1 + BN + ReLU -> t1
// ---------------------------------------------------------------------------
__global__ __launch_bounds__(256) void gconv1_k(const float* __restrict__ a,
                                                const float* __restrict__ w1,
                                                const float* __restrict__ b1,
                                                const float* __restrict__ g1,
                                                const float* __restrict__ be1,
                                                float* __restrict__ t1) {
  int bid = blockIdx.x;
  int b = bid >> 10;
  int r = bid & 1023;
  int o = r >> 4;
  int rc = r & 15;
  int tid = threadIdx.x;
  int px4 = tid & 31;
  int ry = tid >> 5;
  int y = (rc << 3) + ry;
  int x0 = px4 << 2;
  float bv = b1[o];
  float4 acc = make_float4(bv, bv, bv, bv);
#pragma unroll
  for (int ic = 0; ic < 2; ++ic) {
    const float* ap = a + ((size_t)(b * 128 + 2 * o + ic) << 14);
    const float* wr0 = w1 + o * 18 + ic * 9;
#pragma unroll
    for (int dy = 0; dy < 3; ++dy) {
      int yy = y + dy - 1;
      if ((unsigned)yy >= 128u) continue;
      const float* row = ap + (yy << 7);
      float4 mid = *(const float4*)(row + x0);
      float lf = (px4 > 0) ? row[x0 - 1] : 0.f;
      float rt = (px4 < 31) ? row[x0 + 4] : 0.f;
      float wa = wr0[dy * 3 + 0], wb = wr0[dy * 3 + 1], wc = wr0[dy * 3 + 2];
      acc.x += wa * lf    + wb * mid.x + wc * mid.y;
      acc.y += wa * mid.x + wb * mid.y + wc * mid.z;
      acc.z += wa * mid.y + wb * mid.z + wc * mid.w;
      acc.w += wa * mid.z + wb * mid.w + wc * rt;
    }
  }
  const float invs = 0.9999950000374997f;  // 1/sqrt(1+1e-5)
  float s = g1[o] * invs, be = be1[o];
  acc.x = fmaxf(acc.x * s + be, 0.f);
  acc.y = fmaxf(acc.y * s + be, 0.f);
  acc.z = fmaxf(acc.z * s + be, 0.f);
  acc.w = fmaxf(acc.w * s + be, 0.f);
  *(float4*)(t1 + (((size_t)(b << 6) + o) << 14) + (y << 7) + x0) = acc;
}

// ---------------------------------------------------------------------------
// dconv_k: depthwise 3x3 + b3 + BN + ReLU -> t2
// ---------------------------------------------------------------------------
__global__ __launch_bounds__(256) void dconv_k(const float* __restrict__ y2,
                                               const float* __restrict__ w3,
                                               const float* __restrict__ b3,
                                               const float* __restrict__ g2,
                                               const float* __restrict__ be2,
                                               float* __restrict__ t2) {
  int bid = blockIdx.x;
  int b = bid >> 10;
  int r = bid & 1023;
  int o = r >> 4;
  int rc = r & 15;
  int tid = threadIdx.x;
  int px4 = tid & 31;
  int ry = tid >> 5;
  int y = (rc << 3) + ry;
  int x0 = px4 << 2;
  float bv = b3[o];
  float4 acc = make_float4(bv, bv, bv, bv);
  const float* ap = y2 + (((size_t)(b << 6) + o) << 14);
  const float* wr0 = w3 + o * 9;
#pragma unroll
  for (int dy = 0; dy < 3; ++dy) {
    int yy = y + dy - 1;
    if ((unsigned)yy >= 128u) continue;
    const float* row = ap + (yy << 7);
    float4 mid = *(const float4*)(row + x0);
    float lf = (px4 > 0) ? row[x0 - 1] : 0.f;
    float rt = (px4 < 31) ? row[x0 + 4] : 0.f;
    float wa = wr0[dy * 3 + 0], wb = wr0[dy * 3 + 1], wc = wr0[dy * 3 + 2];
    acc.x += wa * lf    + wb * mid.x + wc * mid.y;
    acc.y += wa * mid.x + wb * mid.y + wc * mid.z;
    acc.z += wa * mid.y + wb * mid.z + wc * mid.w;
    acc.w += wa * mid.z + wb * mid.w + wc * rt;
  }
  const float invs = 0.9999950000374997f;
  float s = g2[o] * invs, be = be2[o];
  acc.x = fmaxf(acc.x * s + be, 0.f);
  acc.y = fmaxf(acc.y * s + be, 0.f);
  acc.z = fmaxf(acc.z * s + be, 0.f);
  acc.w = fmaxf(acc.w * s + be, 0.f);
  *(float4*)(t2 + (((size_t)(b << 6) + o) << 14) + (y << 7) + x0) = acc;
}

// ---------------------------------------------------------------------------
// PASS A (4-wide, XCD-swizzled, fp16 nt stores): thread handles n0..n0+3
// (one channel c = n0>>14). Within one kk region addr is linear in t, so the
// 36 reads per array are contiguous; boundary elements masked in VALU.
// XCD swizzle keeps each channel's 16 blocks on ONE XCD (L2-resident reads:
// FETCH 307->12 MB measured round 6). cols stored fp16 nontemporal (written
// once, read once in passB) - halves the dominant write traffic.
// ---------------------------------------------------------------------------
__global__ __launch_bounds__(256) void passA_k(const float* __restrict__ xq,
                                               const float* __restrict__ fgp,
                                               const float* __restrict__ bgp,
                                               _Float16* __restrict__ colsF,
                                               _Float16* __restrict__ colsB,
                                               int b0) {
  int bl = blockIdx.x >> 10;
  int vb = blockIdx.x & 1023;
  int v = ((vb & 7) << 7) + (vb >> 3);           // XCD-chunked swizzle
  int n0 = ((v << 8) + threadIdx.x) << 2;
  int b = b0 + bl;
  const float* xqb = xq + ((size_t)b << 20);
  const float* fgb = fgp + ((size_t)b << 20);
  const float* bgb = bgp + ((size_t)b << 20);
  _Float16* cF = colsF + ((size_t)bl * 9 << 20);
  _Float16* cB = colsB + ((size_t)bl * 9 << 20);
  int c = n0 >> 14;
  int l0 = n0 & 16383;
  int t0 = 9 * l0;
  int r0 = t0 & 16383;
  int kk0 = t0 >> 14;
  float resF[9][4], resB[9][4];

  if (r0 <= 16348) {
    // fast path: whole 36-range in one kk region
    int ki = kk0 / 3, kj = kk0 - 3 * ki;
    int base0 = (c << 14) + r0 + ((ki - 1) << 7) + (kj - 1);
    int kj0 = (kj == 0), kj2 = (kj == 2), ki0 = (ki == 0), ki2 = (ki == 2);
#pragma unroll
    for (int q = 0; q < 4; ++q) {
      int hq = r0 + 9 * q;
      int xg0 = hq & 127, yg0 = hq >> 7;
      const float* px_ = xqb + base0 + 9 * q;
      const float* pf_ = fgb + base0 + 9 * q;
      const float* pb_ = bgb + base0 + 9 * q;
      f4u X0 = *(const f4u*)px_;
      f4u X1 = *(const f4u*)(px_ + 4);
      float X8 = px_[8];
      f4u F0 = *(const f4u*)pf_;
      f4u F1 = *(const f4u*)(pf_ + 4);
      float F8 = pf_[8];
      f4u B0 = *(const f4u*)pb_;
      f4u B1 = *(const f4u*)(pb_ + 4);
      float B8 = pb_[8];
      float XV[9], SF[9], SB[9];
#pragma unroll
      for (int e = 0; e < 9; ++e) {
        int xw = xg0 + e;
        int xp = xw & 127;
        int yp = yg0 + (xw >> 7);
        int inv = (kj0 & (xp == 0)) | (kj2 & (xp == 127)) |
                  (ki0 & (yp == 0)) | (ki2 & (yp == 127));
        float xv = (e < 4) ? X0[e] : ((e < 8) ? X1[e - 4] : X8);
        float fv = (e < 4) ? F0[e] : ((e < 8) ? F1[e - 4] : F8);
        float bv = (e < 4) ? B0[e] : ((e < 8) ? B1[e - 4] : B8);
        XV[e] = inv ? 0.f : xv;
        SF[e] = inv ? 0.f : xv * fv;
        SB[e] = inv ? 0.f : xv - bv;
      }
#pragma unroll
      for (int tr = 0; tr < 3; ++tr) {
        int e = 3 * tr;
        float mf = fmaxf(fmaxf(SF[e], SF[e + 1]), SF[e + 2]);
        float e0 = __expf(SF[e] - mf), e1 = __expf(SF[e + 1] - mf), e2 = __expf(SF[e + 2] - mf);
        float rs = 0.125f / (e0 + e1 + e2);
        resF[e + 0][q] = e0 * rs * XV[e + 0];
        resF[e + 1][q] = e1 * rs * XV[e + 1];
        resF[e + 2][q] = e2 * rs * XV[e + 2];
        float mb = fmaxf(fmaxf(SB[e], SB[e + 1]), SB[e + 2]);
        float g0 = __expf(SB[e] - mb), g1 = __expf(SB[e + 1] - mb), g2 = __expf(SB[e + 2] - mb);
        float rb = 0.125f / (g0 + g1 + g2);
        resB[e + 0][q] = g0 * rb * XV[e + 0];
        resB[e + 1][q] = g1 * rb * XV[e + 1];
        resB[e + 2][q] = g2 * rb * XV[e + 2];
      }
    }
  } else {
    // slow path (~0.2% of threads): kk boundary inside the 36-range
#pragma unroll
    for (int q = 0; q < 4; ++q) {
      float XV[9], SF[9], SB[9];
#pragma unroll
      for (int e = 0; e < 9; ++e) {
        int t = t0 + 9 * q + e;
        int kk = t >> 14;
        int hwp = t & 16383;
        int ki = kk / 3, kj = kk - 3 * ki;
        int sy = (hwp >> 7) + ki - 1;
        int sx = (hwp & 127) + kj - 1;
        float xv = 0.f, sf = 0.f, sb = 0.f;
        if (((unsigned)sy < 128u) && ((unsigned)sx < 128u)) {
          int off = (c << 14) + (sy << 7) + sx;
          xv = xqb[off];
          sf = xv * fgb[off];
          sb = xv - bgb[off];
        }
        XV[e] = xv; SF[e] = sf; SB[e] = sb;
      }
#pragma unroll
      for (int tr = 0; tr < 3; ++tr) {
        int e = 3 * tr;
        float mf = fmaxf(fmaxf(SF[e], SF[e + 1]), SF[e + 2]);
        float e0 = __expf(SF[e] - mf), e1 = __expf(SF[e + 1] - mf), e2 = __expf(SF[e + 2] - mf);
        float rs = 0.125f / (e0 + e1 + e2);
        resF[e + 0][q] = e0 * rs * XV[e + 0];
        resF[e + 1][q] = e1 * rs * XV[e + 1];
        resF[e + 2][q] = e2 * rs * XV[e + 2];
        float mb = fmaxf(fmaxf(SB[e], SB[e + 1]), SB[e + 2]);
        float g0 = __expf(SB[e] - mb), g1 = __expf(SB[e + 1] - mb), g2 = __expf(SB[e + 2] - mb);
        float rb = 0.125f / (g0 + g1 + g2);
        resB[e + 0][q] = g0 * rb * XV[e + 0];
        resB[e + 1][q] = g1 * rb * XV[e + 1];
        resB[e + 2][q] = g2 * rb * XV[e + 2];
      }
    }
  }
#pragma unroll
  for (int m = 0; m < 9; ++m) {
    h4 vF = {(_Float16)resF[m][0], (_Float16)resF[m][1],
             (_Float16)resF[m][2], (_Float16)resF[m][3]};
    h4 vB = {(_Float16)resB[m][0], (_Float16)resB[m][1],
             (_Float16)resB[m][2], (_Float16)resB[m][3]};
    __builtin_nontemporal_store(vF, (h4*)(cF + ((size_t)m << 20) + n0));
    __builtin_nontemporal_store(vB, (h4*)(cB + ((size_t)m << 20) + n0));
  }
}

// ---------------------------------------------------------------------------
// PASS B (8-wide, fp16 nt loads): fold gather. Per thread: 8 consecutive x of
// one (c2,y). Per plane: aligned h8 (16B) + 2 scalar halo halfs. cols read once.
// ---------------------------------------------------------------------------
__global__ __launch_bounds__(256) void passB_k(const _Float16* __restrict__ colsF,
                                               const _Float16* __restrict__ colsB,
                                               float* __restrict__ a, int b0) {
  int bl = blockIdx.x >> 9;
  int idx = ((blockIdx.x & 511) << 8) + threadIdx.x;
  int b = b0 + bl;
  int c2 = idx >> 11;
  int hw0 = (idx << 3) & 16383;
  int y = hw0 >> 7, x0 = hw0 & 127;
  const _Float16* cFb = colsF + ((size_t)bl * 9 << 20);
  const _Float16* cBb = colsB + ((size_t)bl * 9 << 20);
  float af[8], ab[8];
#pragma unroll
  for (int k = 0; k < 8; ++k) { af[k] = 0.f; ab[k] = 0.f; }
#pragma unroll
  for (int i = 0; i < 3; ++i) {
    int yp = y + 1 - i;
    if ((unsigned)yp >= 128u) continue;
#pragma unroll
    for (int j = 0; j < 3; ++j) {
      size_t pb = (((size_t)(c2 * 9 + 3 * i + j)) << 14) + (yp << 7);
      const _Float16* rowF = cFb + pb;
      const _Float16* rowB = cBb + pb;
      h8 mF = __builtin_nontemporal_load((const h8*)(rowF + x0));
      float lfF = (x0 > 0) ? (float)rowF[x0 - 1] : 0.f;
      float rtF = (x0 < 120) ? (float)rowF[x0 + 8] : 0.f;
      h8 mB = __builtin_nontemporal_load((const h8*)(rowB + x0));
      float lfB = (x0 > 0) ? (float)rowB[x0 - 1] : 0.f;
      float rtB = (x0 < 120) ? (float)rowB[x0 + 8] : 0.f;
      float WF[10] = {lfF, (float)mF[0], (float)mF[1], (float)mF[2], (float)mF[3],
                      (float)mF[4], (float)mF[5], (float)mF[6], (float)mF[7], rtF};
      float WB[10] = {lfB, (float)mB[0], (float)mB[1], (float)mB[2], (float)mB[3],
                      (float)mB[4], (float)mB[5], (float)mB[6], (float)mB[7], rtB};
#pragma unroll
      for (int k = 0; k < 8; ++k) {
        af[k] += WF[k + 2 - j];
        ab[k] += WB[k + 2 - j];
      }
    }
  }
  float* aF = a + (((size_t)b * 128 + c2) << 14) + hw0;
  float* aB = a + (((size_t)b * 128 + 64 + c2) << 14) + hw0;
  *(float4*)(aF)     = make_float4(af[0], af[1], af[2], af[3]);
  *(float4*)(aF + 4) = make_float4(af[4], af[5], af[6], af[7]);
  *(float4*)(aB)     = make_float4(ab[0], ab[1], ab[2], ab[3]);
  *(float4*)(aB + 4) = make_float4(ab[4], ab[5], ab[6], ab[7]);
}

// ---------------------------------------------------------------------------
// Fallback fused attn+fold (verified) — used only if ws too small.
// ---------------------------------------------------------------------------
__device__ __forceinline__ void triel(const float* __restrict__ xqb,
                                      const float* __restrict__ fgb,
                                      const float* __restrict__ bgb,
                                      int fe, float& xv, float& sf, float& sb) {
  int u = fe >> 14;
  int hwp = fe & 16383;
  int c = u / 9;
  int kk = u - c * 9;
  int ki = kk / 3;
  int kj = kk - ki * 3;
  int sy = (hwp >> 7) + ki - 1;
  int sx = (hwp & 127) + kj - 1;
  if (((unsigned)sy < 128u) && ((unsigned)sx < 128u)) {
    int off = (c << 14) + (sy << 7) + sx;
    float xv_ = xqb[off];
    xv = xv_;
    sf = xv_ * fgb[off];
    sb = xv_ - bgb[off];
  } else {
    xv = 0.f; sf = 0.f; sb = 0.f;
  }
}

__global__ __launch_bounds__(256) void attnfold_k(const float* __restrict__ xq,
                                                  const float* __restrict__ fgp,
                                                  const float* __restrict__ bgp,
                                                  float* __restrict__ a) {
  int gidx = blockIdx.x * 256 + threadIdx.x;
  int hw = gidx & 16383;
  int bc = gidx >> 14;
  int c2 = bc & 63;
  int b = bc >> 6;
  int y = hw >> 7, x = hw & 127;
  const float* xqb = xq + (b << 20);
  const float* fgb = fgp + (b << 20);
  const float* bgb = bgp + (b << 20);
  float accf = 0.f, accb = 0.f;
#pragma unroll
  for (int i = 0; i < 3; ++i) {
    int yp = y + 1 - i;
    if ((unsigned)yp >= 128u) continue;
#pragma unroll
    for (int j = 0; j < 3; ++j) {
      int xp = x + 1 - j;
      if ((unsigned)xp >= 128u) continue;
      int g = ((c2 * 9 + i * 3 + j) << 14) + (yp << 7) + xp;
      int m = g >> 20;
      int n = g & 1048575;
      int f = n * 9 + m;
      int q = f % 3;
      int f0 = f - q;
      float xv0, sf0, sb0, xv1, sf1, sb1, xv2, sf2, sb2;
      triel(xqb, fgb, bgb, f0,     xv0, sf0, sb0);
      triel(xqb, fgb, bgb, f0 + 1, xv1, sf1, sb1);
      triel(xqb, fgb, bgb, f0 + 2, xv2, sf2, sb2);
      float xsel = (q == 0) ? xv0 : ((q == 1) ? xv1 : xv2);
      float mf = fmaxf(fmaxf(sf0, sf1), sf2);
      float ef0 = __expf(sf0 - mf), ef1 = __expf(sf1 - mf), ef2 = __expf(sf2 - mf);
      float self_f = (q == 0) ? ef0 : ((q == 1) ? ef1 : ef2);
      accf += self_f / (ef0 + ef1 + ef2) * xsel;
      float mb = fmaxf(fmaxf(sb0, sb1), sb2);
      float eb0 = __expf(sb0 - mb), eb1 = __expf(sb1 - mb), eb2 = __expf(sb2 - mb);
      float self_b = (q == 0) ? eb0 : ((q == 1) ? eb1 : eb2);
      accb += self_b / (eb0 + eb1 + eb2) * xsel;
    }
  }
  a[((b * 128 + c2) << 14) + hw] = accf * 0.125f;
  a[((b * 128 + 64 + c2) << 14) + hw] = accb * 0.125f;
}

// ---------------------------------------------------------------------------
extern "C" void kernel_launch(void* const* d_in, const int* in_sizes, int n_in,
                              void* d_out, int out_size, void* d_ws, size_t ws_size,
                              hipStream_t stream) {
  (void)in_sizes; (void)n_in; (void)out_size;
  const float* x      = (const float*)d_in[0];
  const float* fg     = (const float*)d_in[1];
  const float* bg     = (const float*)d_in[2];
  const float* w_x    = (const float*)d_in[3];
  const float* bias_x = (const float*)d_in[4];
  const float* w_f    = (const float*)d_in[5];
  const float* bias_f = (const float*)d_in[6];
  const float* w_b    = (const float*)d_in[7];
  const float* bias_b = (const float*)d_in[8];
  const float* w1     = (const float*)d_in[9];
  const float* b1     = (const float*)d_in[10];
  const float* g1     = (const float*)d_in[11];
  const float* be1    = (const float*)d_in[12];
  const float* w2     = (const float*)d_in[13];
  const float* b2     = (const float*)d_in[14];
  const float* w3     = (const float*)d_in[15];
  const float* b3     = (const float*)d_in[16];
  const float* g2     = (const float*)d_in[17];
  const float* be2    = (const float*)d_in[18];
  const float* w4     = (const float*)d_in[19];
  const float* b4     = (const float*)d_in[20];
  float* out = (float*)d_out;
  float* ws  = (float*)d_ws;

  const size_t NCHWf = (size_t)NB * 64 * HWSZ;  // 4,194,304 floats
  // 256-float front pad: passA fast-path windows can underrun the first
  // plane by up to ~130 floats (masked lanes) — keep reads in-bounds.
  float* base = ws + 256;
  float* xq  = base;
  float* fgp = base + NCHWf;
  float* bgp = base + 2 * NCHWf;
  float* a   = base + 3 * NCHWf;                // 2*NCHWf floats
  _Float16* colsbase = (_Float16*)(base + 5 * NCHWf);
  // dead-buffer reuse for the tail chain:
  float* t1 = fgp;   // fgp dead after passA
  float* y2 = xq;    // xq dead after passA
  float* t2 = bgp;   // bgp dead after passA

  dim3 blk(256);
  pw3_k<<<3 * NB * 256, blk, 0, stream>>>(x, fg, bg, w_x, w_f, w_b,
                                          bias_x, bias_f, bias_b, xq, fgp, bgp);

  // cols workspace: per batch, colsF + colsB = 18M halfs = 37.75 MB.
  const size_t usedB = (5 * NCHWf + 512) * 4;
  const size_t perBatchColsB = ((size_t)18 << 20) * 2;  // bytes
  size_t availB = (ws_size > usedB) ? (ws_size - usedB) : 0;
  int fit = (int)(availB / perBatchColsB);
  if (fit > NB) fit = NB;

  if (fit >= 1) {
    _Float16* colsF = colsbase;
    _Float16* colsB = colsbase + ((size_t)fit * 9 << 20);
    for (int b0 = 0; b0 < NB; b0 += fit) {
      int nb = (NB - b0 < fit) ? (NB - b0) : fit;
      passA_k<<<nb * 1024, blk, 0, stream>>>(xq, fgp, bgp, colsF, colsB, b0);
      passB_k<<<nb * 512, blk, 0, stream>>>(colsF, colsB, a, b0);
    }
  } else {
    attnfold_k<<<NB * 64 * HWSZ / 256, blk, 0, stream>>>(xq, fgp, bgp, a);
  }

  gconv1_k<<<NB * 1024, blk, 0, stream>>>(a, w1, b1, g1, be1, t1);
  pw_k<<<NB * 256, blk, 0, stream>>>(t1, w2, b2, y2);
  dconv_k<<<NB * 1024, blk, 0, stream>>>(y2, w3, b3, g2, be2, t2);
  pw_k<<<NB * 256, blk, 0, stream>>>(t2, w4, b4, out);
}